// Round 9
// baseline (262.148 us; speedup 1.0000x reference)
//
#include <hip/hip_runtime.h>

#define N_NODES 131072
#define NE      2097152
#define CIN     64
#define HID     64
#define H2X     128   // 2*HID
#define NODESG  128   // nodes per graph
#define NGRAPH  1024
#define NCLS    4

#define NBUCK   256   // buckets = dst>>9
#define NPB     512   // nodes per bucket
#define HBLK    1024  // histogram blocks
#define EPB     2048  // edges per histogram/scatter block
#define STAGE_CAP 10240  // LDS edge stage per bucket (Poisson(8192) max ~8.5K)
#define DEGSC   1048576.0f   // 2^20 fixed-point for LDS deg accumulation
#define DEGMASK ((1ull << 40) - 1)

typedef short bf16x8 __attribute__((ext_vector_type(8)));
typedef float f32x4  __attribute__((ext_vector_type(4)));

// bf16 helpers (RNE; inputs finite)
__device__ __forceinline__ unsigned short f2b(float f) {
    unsigned int u = __float_as_uint(f);
    return (unsigned short)((u + 0x7fffu + ((u >> 16) & 1u)) >> 16);
}
__device__ __forceinline__ unsigned int pack2(float a, float b) {
    return (unsigned int)f2b(a) | ((unsigned int)f2b(b) << 16);
}
__device__ __forceinline__ float blo(unsigned u) { return __uint_as_float(u << 16); }
__device__ __forceinline__ float bhi(unsigned u) { return __uint_as_float(u & 0xffff0000u); }

// ---------------- W1/W2 -> global MFMA B-frag tables (once) ----------------
// 8 blocks (0-3: W1, 4-7: W2).

__global__ __launch_bounds__(256) void k_wswiz(
        const float* __restrict__ W1, const float* __restrict__ W2,
        unsigned short* __restrict__ wf1, unsigned short* __restrict__ wf2) {
    int tid = threadIdx.x;
    int b = blockIdx.x;
    int idx = (b & 3) * 256 + tid;                // 0..1023
    if (b < 4) {
        // W1: 16 frags (kt<2, nt<8) x 64 lanes
        int kt = idx >> 9, nt = (idx >> 6) & 7, l = idx & 63;
        int lm = l & 15, lq = l >> 4;
        unsigned pk[4];
        #pragma unroll
        for (int jp = 0; jp < 4; ++jp) {
            float w0 = W1[(kt*32 + lq*8 + 2*jp)     * H2X + nt*16 + lm];
            float w1 = W1[(kt*32 + lq*8 + 2*jp + 1) * H2X + nt*16 + lm];
            pk[jp] = pack2(w0, w1);
        }
        *(uint4*)&wf1[idx * 8] = make_uint4(pk[0], pk[1], pk[2], pk[3]);
    } else {
        // W2: 16 frags (kt<4, nt<4) x 64 lanes
        int kt = idx >> 8, nt = (idx >> 6) & 3, l = idx & 63;
        int lm = l & 15, lq = l >> 4;
        unsigned pk[4];
        #pragma unroll
        for (int jp = 0; jp < 4; ++jp) {
            float w0 = W2[(kt*32 + lq*8 + 2*jp)     * HID + nt*16 + lm];
            float w1 = W2[(kt*32 + lq*8 + 2*jp + 1) * HID + nt*16 + lm];
            pk[jp] = pack2(w0, w1);
        }
        *(uint4*)&wf2[idx * 8] = make_uint4(pk[0], pk[1], pk[2], pk[3]);
    }
}

// ---------------- bucketed counting sort (no global atomics) ----------------

__global__ __launch_bounds__(256) void k_hist(const int* __restrict__ dst,
                                              int* __restrict__ hist) {
    __shared__ unsigned bh[NBUCK];
    int t = threadIdx.x;
    bh[t] = 0;
    __syncthreads();
    int base = blockIdx.x * EPB;
    #pragma unroll
    for (int k = 0; k < EPB / 256; ++k) {
        int d = dst[base + t + 256 * k];
        atomicAdd(&bh[d >> 9], 1u);
    }
    __syncthreads();
    hist[t * HBLK + blockIdx.x] = (int)bh[t];   // bucket-major layout
}

__global__ void k_scan1(const int* __restrict__ in, int* __restrict__ out,
                        int* __restrict__ partial) {
    __shared__ int sd[256];
    int t = threadIdx.x;
    int base = blockIdx.x * 512;
    int c0 = in[base + 2*t];
    int c1 = in[base + 2*t + 1];
    int loc = c0 + c1;
    sd[t] = loc;
    __syncthreads();
    for (int off = 1; off < 256; off <<= 1) {
        int v = (t >= off) ? sd[t - off] : 0;
        __syncthreads();
        sd[t] += v;
        __syncthreads();
    }
    int excl = sd[t] - loc;
    out[base + 2*t]     = excl;
    out[base + 2*t + 1] = excl + c0;
    if (t == 255) partial[blockIdx.x] = sd[t];
}

__global__ void k_scan2(int* __restrict__ partial) {
    __shared__ int sd[256];
    int t = threadIdx.x;
    int p0 = partial[2*t], p1 = partial[2*t + 1];
    int loc = p0 + p1;
    sd[t] = loc;
    __syncthreads();
    for (int off = 1; off < 256; off <<= 1) {
        int v = (t >= off) ? sd[t - off] : 0;
        __syncthreads();
        sd[t] += v;
        __syncthreads();
    }
    int excl = sd[t] - loc;
    partial[2*t]     = excl;
    partial[2*t + 1] = excl + p0;
}

// scatter edges into bucket-major order; global base = hist(local scan) + partial
__global__ __launch_bounds__(256) void k_scatter(
        const int* __restrict__ src, const int* __restrict__ dst,
        const float* __restrict__ ew, const int* __restrict__ hist,
        const int* __restrict__ partial, unsigned long long* __restrict__ part) {
    __shared__ unsigned lcur[NBUCK];
    int t = threadIdx.x;
    int gi = t * HBLK + blockIdx.x;
    lcur[t] = (unsigned)(hist[gi] + partial[gi >> 9]);
    __syncthreads();
    int base = blockIdx.x * EPB;
    #pragma unroll
    for (int k = 0; k < EPB / 256; ++k) {
        int e = base + t + 256 * k;
        int s = src[e], d = dst[e];
        unsigned w = __float_as_uint(ew[e]);
        unsigned p = atomicAdd(&lcur[d >> 9], 1u);
        part[p] = ((unsigned long long)w << 32) |
                  ((unsigned long long)(unsigned)(d & 511) << 17) |
                  (unsigned long long)(unsigned)s;
    }
}

// one block per bucket: SINGLE global pass (r9): stage the bucket's edges in
// LDS (80KB, overflow-guarded), count+deg from the staged read, LDS scan ->
// rowptr, rank-scatter to csr FROM LDS (saves the 16MB part[] re-read).
// Tail: fused xcast for this bucket's 512 nodes (dis is already in LDS) --
// removes the separate k_xcast kernel + its launch/drain + dis re-read.
__global__ __launch_bounds__(256) void k_bucket(
        const unsigned long long* __restrict__ part, const int* __restrict__ hist,
        const int* __restrict__ partial, int2* __restrict__ csr,
        int* __restrict__ rowptr, int* __restrict__ counts, float* __restrict__ dis,
        const float* __restrict__ x, uint2* __restrict__ xb2) {
    __shared__ unsigned long long stage[STAGE_CAP];  // 80KB edge stage
    __shared__ unsigned long long dc[NPB];   // count<<40 | deg-fixed-point
    __shared__ unsigned cnt2[NPB];
    __shared__ int rp[NPB];
    __shared__ int sd[256];
    __shared__ float sdis[NPB];
    int t = threadIdx.x, b = blockIdx.x;
    dc[t] = 0; dc[t + 256] = 0;
    cnt2[t] = 0; cnt2[t + 256] = 0;
    __syncthreads();
    int start = hist[b * HBLK] + partial[2 * b];
    int end   = (b == NBUCK - 1) ? NE : (hist[(b + 1) * HBLK] + partial[2 * (b + 1)]);

    for (int j = start + t; j < end; j += 256) {
        unsigned long long p = part[j];
        int loc = j - start;
        if (loc < STAGE_CAP) stage[loc] = p;     // overflow: re-read in pass 2
        unsigned dl = (unsigned)(p >> 17) & 511u;
        float w = __uint_as_float((unsigned)(p >> 32));
        atomicAdd(&dc[dl], (1ull << 40) | (unsigned long long)(unsigned)(w * DEGSC));
    }
    __syncthreads();

    unsigned long long d0 = dc[2*t], d1 = dc[2*t + 1];
    int c0 = (int)(d0 >> 40), c1 = (int)(d1 >> 40);
    int loc = c0 + c1;
    sd[t] = loc;
    __syncthreads();
    for (int off = 1; off < 256; off <<= 1) {
        int v = (t >= off) ? sd[t - off] : 0;
        __syncthreads();
        sd[t] += v;
        __syncthreads();
    }
    int excl = sd[t] - loc;
    rp[2*t] = excl; rp[2*t + 1] = excl + c0;

    int n0 = b * NPB;
    rowptr[n0 + 2*t]     = start + excl;
    rowptr[n0 + 2*t + 1] = start + excl + c0;
    counts[n0 + 2*t]     = c0;
    counts[n0 + 2*t + 1] = c1;
    float dg0 = (float)(d0 & DEGMASK) * (1.0f / DEGSC);
    float dg1 = (float)(d1 & DEGMASK) * (1.0f / DEGSC);
    float di0 = rsqrtf(dg0 + 1.0f);
    float di1 = rsqrtf(dg1 + 1.0f);
    dis[n0 + 2*t]     = di0;
    dis[n0 + 2*t + 1] = di1;
    sdis[2*t]     = di0;
    sdis[2*t + 1] = di1;
    __syncthreads();

    for (int j = start + t; j < end; j += 256) {
        int lo = j - start;
        unsigned long long p = (lo < STAGE_CAP) ? stage[lo] : part[j];
        unsigned dl = (unsigned)(p >> 17) & 511u;
        int s = (int)(p & 0x1ffffu);
        unsigned r = atomicAdd(&cnt2[dl], 1u);
        csr[start + rp[dl] + (int)r] = make_int2(s, (int)(unsigned)(p >> 32)); // raw ew
    }

    // fused xcast: xb2[node] = bf16(dis[node] * x[node]) for this bucket's nodes
    const float4* x4 = (const float4*)x + (size_t)n0 * 16;
    uint2* y2 = xb2 + (size_t)n0 * 16;
    #pragma unroll 4
    for (int i = t; i < NPB * 16; i += 256) {
        float d = sdis[i >> 4];
        float4 v = x4[i];
        y2[i] = make_uint2(pack2(d * v.x, d * v.y), pack2(d * v.z, d * v.w));
    }
}

// ---- shared gather-pair macro body: quarter-wave (16 lanes/edge, 4 ch/lane) ----
// r8 CONCLUSION (final for the gathers): streaming body @ bounds(256,8) fits
// the 8-wave tier (VGPR 32, no spill); occupancy 42->65% bought only -3% =>
// gather is bandwidth-bound at ~2.7 TB/s fetch = ~1 L2-miss line/cycle/XCD on
// compulsory traffic (123MB = Poisson floor). DO NOT TOUCH the gather kernels.

#define GATHER_PAIR(TAB, pA, pB, nA, nB, cmA, cmB, a0,a1,a2,a3, b0,b1,b2,b3, vSA, vSB) \
    {                                                                                  \
        int   sA0 = __shfl(pA.x, qid),      sA1 = __shfl(pA.x, qid + 4);               \
        int   sA2 = __shfl(pA.x, qid + 8),  sA3 = __shfl(pA.x, qid + 12);              \
        float fA0 = __int_as_float(__shfl(pA.y, qid));                                 \
        float fA1 = __int_as_float(__shfl(pA.y, qid + 4));                             \
        float fA2 = __int_as_float(__shfl(pA.y, qid + 8));                             \
        float fA3 = __int_as_float(__shfl(pA.y, qid + 12));                            \
        int   sB0 = __shfl(pB.x, qid),      sB1 = __shfl(pB.x, qid + 4);               \
        int   sB2 = __shfl(pB.x, qid + 8),  sB3 = __shfl(pB.x, qid + 12);              \
        float fB0 = __int_as_float(__shfl(pB.y, qid));                                 \
        float fB1 = __int_as_float(__shfl(pB.y, qid + 4));                             \
        float fB2 = __int_as_float(__shfl(pB.y, qid + 8));                             \
        float fB3 = __int_as_float(__shfl(pB.y, qid + 12));                            \
        uint2 vA0 = TAB[((unsigned)sA0 << 4) | ql];                                    \
        uint2 vA1 = TAB[((unsigned)sA1 << 4) | ql];                                    \
        uint2 vA2 = TAB[((unsigned)sA2 << 4) | ql];                                    \
        uint2 vA3 = TAB[((unsigned)sA3 << 4) | ql];                                    \
        uint2 vB0 = TAB[((unsigned)sB0 << 4) | ql];                                    \
        uint2 vB1 = TAB[((unsigned)sB1 << 4) | ql];                                    \
        uint2 vB2 = TAB[((unsigned)sB2 << 4) | ql];                                    \
        uint2 vB3 = TAB[((unsigned)sB3 << 4) | ql];                                    \
        vSA = TAB[((unsigned)nA << 4) | ql];                                           \
        vSB = TAB[((unsigned)nB << 4) | ql];                                           \
        a0 = fmaf(fA0, blo(vA0.x), a0); a1 = fmaf(fA0, bhi(vA0.x), a1);                \
        a2 = fmaf(fA0, blo(vA0.y), a2); a3 = fmaf(fA0, bhi(vA0.y), a3);                \
        a0 = fmaf(fA1, blo(vA1.x), a0); a1 = fmaf(fA1, bhi(vA1.x), a1);                \
        a2 = fmaf(fA1, blo(vA1.y), a2); a3 = fmaf(fA1, bhi(vA1.y), a3);                \
        a0 = fmaf(fA2, blo(vA2.x), a0); a1 = fmaf(fA2, bhi(vA2.x), a1);                \
        a2 = fmaf(fA2, blo(vA2.y), a2); a3 = fmaf(fA2, bhi(vA2.y), a3);                \
        a0 = fmaf(fA3, blo(vA3.x), a0); a1 = fmaf(fA3, bhi(vA3.x), a1);                \
        a2 = fmaf(fA3, blo(vA3.y), a2); a3 = fmaf(fA3, bhi(vA3.y), a3);                \
        b0 = fmaf(fB0, blo(vB0.x), b0); b1 = fmaf(fB0, bhi(vB0.x), b1);                \
        b2 = fmaf(fB0, blo(vB0.y), b2); b3 = fmaf(fB0, bhi(vB0.y), b3);                \
        b0 = fmaf(fB1, blo(vB1.x), b0); b1 = fmaf(fB1, bhi(vB1.x), b1);                \
        b2 = fmaf(fB1, blo(vB1.y), b2); b3 = fmaf(fB1, bhi(vB1.y), b3);                \
        b0 = fmaf(fB2, blo(vB2.x), b0); b1 = fmaf(fB2, bhi(vB2.x), b1);                \
        b2 = fmaf(fB2, blo(vB2.y), b2); b3 = fmaf(fB2, bhi(vB2.y), b3);                \
        b0 = fmaf(fB3, blo(vB3.x), b0); b1 = fmaf(fB3, bhi(vB3.x), b1);                \
        b2 = fmaf(fB3, blo(vB3.y), b2); b3 = fmaf(fB3, bhi(vB3.y), b3);                \
        int tsA = (cmA > 16) ? ((cmA - 13) >> 2) : 0;                                  \
        int tsB = (cmB > 16) ? ((cmB - 13) >> 2) : 0;                                  \
        int tsM = tsA > tsB ? tsA : tsB;                                               \
        if (tsM > 0) {                                                                 \
            int jj0 = 16 + qid;                                                        \
            float tfA = __int_as_float(__shfl(pA.y, jj0));                             \
            float tfB = __int_as_float(__shfl(pB.y, jj0));                             \
            uint2 tvA = TAB[((unsigned)__shfl(pA.x, jj0) << 4) | ql];                  \
            uint2 tvB = TAB[((unsigned)__shfl(pB.x, jj0) << 4) | ql];                  \
            for (int k = 1; k < tsM; ++k) {                                            \
                int jj = 16 + 4 * k + qid;                                             \
                float nfA = __int_as_float(__shfl(pA.y, jj));                          \
                float nfB = __int_as_float(__shfl(pB.y, jj));                          \
                uint2 nvA = TAB[((unsigned)__shfl(pA.x, jj) << 4) | ql];               \
                uint2 nvB = TAB[((unsigned)__shfl(pB.x, jj) << 4) | ql];               \
                a0 = fmaf(tfA, blo(tvA.x), a0); a1 = fmaf(tfA, bhi(tvA.x), a1);        \
                a2 = fmaf(tfA, blo(tvA.y), a2); a3 = fmaf(tfA, bhi(tvA.y), a3);        \
                b0 = fmaf(tfB, blo(tvB.x), b0); b1 = fmaf(tfB, bhi(tvB.x), b1);        \
                b2 = fmaf(tfB, blo(tvB.y), b2); b3 = fmaf(tfB, bhi(tvB.y), b3);        \
                tfA = nfA; tfB = nfB; tvA = nvA; tvB = nvB;                            \
            }                                                                          \
            a0 = fmaf(tfA, blo(tvA.x), a0); a1 = fmaf(tfA, bhi(tvA.x), a1);            \
            a2 = fmaf(tfA, blo(tvA.y), a2); a3 = fmaf(tfA, bhi(tvA.y), a3);            \
            b0 = fmaf(tfB, blo(tvB.x), b0); b1 = fmaf(tfB, bhi(tvB.x), b1);            \
            b2 = fmaf(tfB, blo(tvB.y), b2); b3 = fmaf(tfB, bhi(tvB.y), b3);            \
        }                                                                              \
        a0 += __shfl_xor(a0, 16); a1 += __shfl_xor(a1, 16);                            \
        a2 += __shfl_xor(a2, 16); a3 += __shfl_xor(a3, 16);                            \
        a0 += __shfl_xor(a0, 32); a1 += __shfl_xor(a1, 32);                            \
        a2 += __shfl_xor(a2, 32); a3 += __shfl_xor(a3, 32);                            \
        b0 += __shfl_xor(b0, 16); b1 += __shfl_xor(b1, 16);                            \
        b2 += __shfl_xor(b2, 16); b3 += __shfl_xor(b3, 16);                            \
        b0 += __shfl_xor(b0, 32); b1 += __shfl_xor(b1, 32);                            \
        b2 += __shfl_xor(b2, 32); b3 += __shfl_xor(b3, 32);                            \
    }

// -------- fused layer 1+2-GEMM: t2u = bf16( dis * (relu((A_hat x)W1 + b1)) W2 ) ----

__global__ __launch_bounds__(256, 8) void k_layer1(
        const uint2* __restrict__ xb2, const int2* __restrict__ csr,
        const int* __restrict__ rowptr, const int* __restrict__ counts,
        const float* __restrict__ dis, const unsigned short* __restrict__ wf1,
        const unsigned short* __restrict__ wf2, const float* __restrict__ b1,
        unsigned short* __restrict__ t2u) {
    __shared__ unsigned short smem[32 * 136];     // union: sagg[32][72] then sh1[32][136]
    unsigned short (*sagg_b)[72]  = (unsigned short (*)[72])smem;
    unsigned short (*sh1)[136]    = (unsigned short (*)[136])smem;
    int tid = threadIdx.x;

    int wave = tid >> 6, lane = tid & 63;
    int qid = lane >> 4, ql = lane & 15;
    int n0 = blockIdx.x * 32;
    int nb = n0 + wave * 8;

    #pragma unroll 1
    for (int ip = 0; ip < 8; ip += 2) {
        int nA = nb + ip, nB = nA + 1;
        int cA = counts[nA], cB = counts[nB];
        int rsA = rowptr[nA], rsB = rowptr[nB];
        float dnA = dis[nA], dnB = dis[nB];
        int cmA = cA < 64 ? cA : 64, cmB = cB < 64 ? cB : 64;
        int2 pA = (lane < cmA) ? csr[rsA + lane] : make_int2(0, 0);
        int2 pB = (lane < cmB) ? csr[rsB + lane] : make_int2(0, 0);
        float a0 = 0.f, a1 = 0.f, a2 = 0.f, a3 = 0.f;
        float b0 = 0.f, b1v = 0.f, b2v = 0.f, b3 = 0.f;
        uint2 vSA, vSB;
        GATHER_PAIR(xb2, pA, pB, nA, nB, cmA, cmB,
                    a0, a1, a2, a3, b0, b1v, b2v, b3, vSA, vSB);
        if (cA > 64) {                             // essentially never
            for (int jj = 64; jj < cA; ++jj) {
                int2 p = csr[rsA + jj];
                float f = __int_as_float(p.y);
                uint2 v = xb2[((unsigned)p.x << 4) | ql];
                if (qid == 0) {
                    a0 += f * blo(v.x); a1 += f * bhi(v.x);
                    a2 += f * blo(v.y); a3 += f * bhi(v.y);
                }
            }
        }
        if (cB > 64) {
            for (int jj = 64; jj < cB; ++jj) {
                int2 p = csr[rsB + jj];
                float f = __int_as_float(p.y);
                uint2 v = xb2[((unsigned)p.x << 4) | ql];
                if (qid == 0) {
                    b0 += f * blo(v.x); b1v += f * bhi(v.x);
                    b2v += f * blo(v.y); b3 += f * bhi(v.y);
                }
            }
        }
        if (qid == 0) {
            int m = wave * 8 + ip;
            *(uint2*)&sagg_b[m][ql * 4] =
                make_uint2(pack2(dnA * (a0 + blo(vSA.x)), dnA * (a1 + bhi(vSA.x))),
                           pack2(dnA * (a2 + blo(vSA.y)), dnA * (a3 + bhi(vSA.y))));
            *(uint2*)&sagg_b[m + 1][ql * 4] =
                make_uint2(pack2(dnB * (b0 + blo(vSB.x)), dnB * (b1v + bhi(vSB.x))),
                           pack2(dnB * (b2v + blo(vSB.y)), dnB * (b3 + bhi(vSB.y))));
        }
    }
    __syncthreads();

    // MFMA GEMM 1: agg(32x64) @ W1(64x128) -> relu+bias -> sh1 (bf16)
    int mt = wave & 1, ntb = (wave >> 1) * 4;
    int lm = lane & 15, lq = lane >> 4;
    float bs[4];
    #pragma unroll
    for (int t = 0; t < 4; ++t) bs[t] = b1[(ntb + t) * 16 + lm];   // L1/L2-hot
    bf16x8 af0 = *(const bf16x8*)&sagg_b[mt*16 + lm][lq * 8];
    bf16x8 af1 = *(const bf16x8*)&sagg_b[mt*16 + lm][32 + lq * 8];
    __syncthreads();   // sagg fully read (in regs) before sh1 overwrites the union
    #pragma unroll
    for (int t = 0; t < 4; ++t) {
        int nt = ntb + t;
        bf16x8 bf0 = *(const bf16x8*)&wf1[(nt*64 + lane) * 8];
        bf16x8 bf1 = *(const bf16x8*)&wf1[((8 + nt)*64 + lane) * 8];
        f32x4 acc = {0.f, 0.f, 0.f, 0.f};
        acc = __builtin_amdgcn_mfma_f32_16x16x32_bf16(af0, bf0, acc, 0, 0, 0);
        acc = __builtin_amdgcn_mfma_f32_16x16x32_bf16(af1, bf1, acc, 0, 0, 0);
        int ch = nt*16 + lm;
        float bias = bs[t];
        #pragma unroll
        for (int r = 0; r < 4; ++r)
            sh1[mt*16 + lq*4 + r][ch] = f2b(fmaxf(acc[r] + bias, 0.f));
    }
    __syncthreads();

    // MFMA GEMM 2: sh1(32x128) @ W2(128x64) -> t2u = bf16(dis * .)
    #pragma unroll
    for (int ti = 0; ti < 2; ++ti) {
        int t = wave * 2 + ti;                    // 8 tiles: 2 mt x 4 nt
        int mt2 = t & 1, nt2 = t >> 1;
        f32x4 acc = {0.f, 0.f, 0.f, 0.f};
        #pragma unroll
        for (int kt = 0; kt < 4; ++kt) {
            bf16x8 af = *(const bf16x8*)&sh1[mt2*16 + lm][kt*32 + lq*8];
            bf16x8 bf = *(const bf16x8*)&wf2[((kt*4 + nt2)*64 + lane) * 8];
            acc = __builtin_amdgcn_mfma_f32_16x16x32_bf16(af, bf, acc, 0, 0, 0);
        }
        int ch = nt2*16 + lm;
        #pragma unroll
        for (int r = 0; r < 4; ++r) {
            int node = n0 + mt2*16 + lq*4 + r;
            t2u[(size_t)node * HID + ch] = f2b(dis[node] * acc[r]);
        }
    }
}

// ---------------- layer 2 aggregation: h2b = bf16(relu( dn*(sum ew*t2y + t2y[n]) + b2 ))
// NOTE (r12 lesson): do NOT fuse load-dependent epilogues (e.g. FC Wfc loads)
// into this loop's tail — added load->use chains under quarter-lane divergence
// cost +23us. Stores are fine; loads are not.

__global__ __launch_bounds__(256, 8) void k_agg2(
        const uint2* __restrict__ t2y, const int2* __restrict__ csr,
        const int* __restrict__ rowptr, const int* __restrict__ counts,
        const float* __restrict__ dis, const float* __restrict__ b2,
        unsigned short* __restrict__ h2b) {
    int tid = threadIdx.x;
    int wave = tid >> 6, lane = tid & 63;
    int qid = lane >> 4, ql = lane & 15;
    float4 bb = *(const float4*)&b2[ql * 4];
    int n0 = blockIdx.x * 32;
    int nb = n0 + wave * 8;

    #pragma unroll 1
    for (int ip = 0; ip < 8; ip += 2) {
        int nA = nb + ip, nB = nA + 1;
        int cA = counts[nA], cB = counts[nB];
        int rsA = rowptr[nA], rsB = rowptr[nB];
        float dnA = dis[nA], dnB = dis[nB];
        int cmA = cA < 64 ? cA : 64, cmB = cB < 64 ? cB : 64;
        int2 pA = (lane < cmA) ? csr[rsA + lane] : make_int2(0, 0);
        int2 pB = (lane < cmB) ? csr[rsB + lane] : make_int2(0, 0);
        float a0 = 0.f, a1 = 0.f, a2 = 0.f, a3 = 0.f;
        float b0 = 0.f, b1v = 0.f, b2v = 0.f, b3 = 0.f;
        uint2 vSA, vSB;
        GATHER_PAIR(t2y, pA, pB, nA, nB, cmA, cmB,
                    a0, a1, a2, a3, b0, b1v, b2v, b3, vSA, vSB);
        if (cA > 64) {
            for (int jj = 64; jj < cA; ++jj) {
                int2 p = csr[rsA + jj];
                float f = __int_as_float(p.y);
                uint2 v = t2y[((unsigned)p.x << 4) | ql];
                if (qid == 0) {
                    a0 += f * blo(v.x); a1 += f * bhi(v.x);
                    a2 += f * blo(v.y); a3 += f * bhi(v.y);
                }
            }
        }
        if (cB > 64) {
            for (int jj = 64; jj < cB; ++jj) {
                int2 p = csr[rsB + jj];
                float f = __int_as_float(p.y);
                uint2 v = t2y[((unsigned)p.x << 4) | ql];
                if (qid == 0) {
                    b0 += f * blo(v.x); b1v += f * bhi(v.x);
                    b2v += f * blo(v.y); b3 += f * bhi(v.y);
                }
            }
        }
        if (qid == 0) {
            float oa0 = fmaxf(fmaf(dnA, a0 + blo(vSA.x), bb.x), 0.f);
            float oa1 = fmaxf(fmaf(dnA, a1 + bhi(vSA.x), bb.y), 0.f);
            float oa2 = fmaxf(fmaf(dnA, a2 + blo(vSA.y), bb.z), 0.f);
            float oa3 = fmaxf(fmaf(dnA, a3 + bhi(vSA.y), bb.w), 0.f);
            float ob0 = fmaxf(fmaf(dnB, b0 + blo(vSB.x), bb.x), 0.f);
            float ob1 = fmaxf(fmaf(dnB, b1v + bhi(vSB.x), bb.y), 0.f);
            float ob2 = fmaxf(fmaf(dnB, b2v + blo(vSB.y), bb.z), 0.f);
            float ob3 = fmaxf(fmaf(dnB, b3 + bhi(vSB.y), bb.w), 0.f);
            *(uint2*)&h2b[((unsigned)nA << 6) | (ql * 4)] =
                make_uint2(pack2(oa0, oa1), pack2(oa2, oa3));
            *(uint2*)&h2b[((unsigned)nB << 6) | (ql * 4)] =
                make_uint2(pack2(ob0, ob1), pack2(ob2, ob3));
        }
    }
}

// ---------------- FC + softmax (bf16 h2) ----------------

__global__ __launch_bounds__(256) void k_fc(
        const unsigned short* __restrict__ h2b, const float* __restrict__ Wfc,
        const float* __restrict__ bfc, float* __restrict__ out) {
    __shared__ float4 red[256];
    int b = blockIdx.x, t = threadIdx.x;
    const uint2* hrow = (const uint2*)(h2b + (size_t)b * (HID * NODESG));
    const float4* W4 = (const float4*)Wfc;
    float4 a = make_float4(0.f, 0.f, 0.f, 0.f);
    #pragma unroll
    for (int j = 0; j < 8; ++j) {
        int i = j * 256 + t;                    // uint2 index: 4 channels
        uint2 hv = hrow[i];
        float h0 = blo(hv.x), h1 = bhi(hv.x), h2v = blo(hv.y), h3 = bhi(hv.y);
        float4 w0 = W4[i * 4 + 0];
        float4 w1 = W4[i * 4 + 1];
        float4 w2 = W4[i * 4 + 2];
        float4 w3 = W4[i * 4 + 3];
        a.x = fmaf(h0, w0.x, a.x); a.y = fmaf(h0, w0.y, a.y);
        a.z = fmaf(h0, w0.z, a.z); a.w = fmaf(h0, w0.w, a.w);
        a.x = fmaf(h1, w1.x, a.x); a.y = fmaf(h1, w1.y, a.y);
        a.z = fmaf(h1, w1.z, a.z); a.w = fmaf(h1, w1.w, a.w);
        a.x = fmaf(h2v, w2.x, a.x); a.y = fmaf(h2v, w2.y, a.y);
        a.z = fmaf(h2v, w2.z, a.z); a.w = fmaf(h2v, w2.w, a.w);
        a.x = fmaf(h3, w3.x, a.x); a.y = fmaf(h3, w3.y, a.y);
        a.z = fmaf(h3, w3.z, a.z); a.w = fmaf(h3, w3.w, a.w);
    }
    red[t] = a;
    __syncthreads();
    for (int s = 128; s > 0; s >>= 1) {
        if (t < s) {
            red[t].x += red[t + s].x; red[t].y += red[t + s].y;
            red[t].z += red[t + s].z; red[t].w += red[t + s].w;
        }
        __syncthreads();
    }
    if (t == 0) {
        float l0 = red[0].x + bfc[0];
        float l1 = red[0].y + bfc[1];
        float l2 = red[0].z + bfc[2];
        float l3 = red[0].w + bfc[3];
        float mx = fmaxf(fmaxf(l0, l1), fmaxf(l2, l3));
        float e0 = expf(l0 - mx), e1 = expf(l1 - mx);
        float e2 = expf(l2 - mx), e3 = expf(l3 - mx);
        float inv = 1.f / (e0 + e1 + e2 + e3);
        float4 o = make_float4(e0 * inv, e1 * inv, e2 * inv, e3 * inv);
        *(float4*)&out[(size_t)b * 4] = o;
    }
}

// ---------------- launch ----------------

extern "C" void kernel_launch(void* const* d_in, const int* in_sizes, int n_in,
                              void* d_out, int out_size, void* d_ws, size_t ws_size,
                              hipStream_t stream) {
    const float* x   = (const float*)d_in[0];
    const int*   ei  = (const int*)  d_in[1];
    const float* ea  = (const float*)d_in[2];
    const float* W1  = (const float*)d_in[3];
    const float* b1  = (const float*)d_in[4];
    const float* W2  = (const float*)d_in[5];
    const float* b2  = (const float*)d_in[6];
    const float* Wfc = (const float*)d_in[7];
    const float* bfc = (const float*)d_in[8];
    float* out = (float*)d_out;
    const int* src = ei;
    const int* dst = ei + NE;

    char* ws = (char*)d_ws;
    size_t off = 0;
    int*   hist   = (int*)  (ws + off); off += (size_t)NBUCK * HBLK * 4;  // 1 MB
    int*   partial= (int*)  (ws + off); off += 4096;
    int*   counts = (int*)  (ws + off); off += (size_t)N_NODES * 4;
    int*   rowptr = (int*)  (ws + off); off += (size_t)N_NODES * 4;
    float* dis    = (float*)(ws + off); off += (size_t)N_NODES * 4;
    unsigned short* wf1 = (unsigned short*)(ws + off); off += 8192 * 2;   // 16 KB
    unsigned short* wf2 = (unsigned short*)(ws + off); off += 8192 * 2;   // 16 KB
    int2*  csr    = (int2*) (ws + off); off += (size_t)NE * 8;
    uint2* xb2    = (uint2*)(ws + off); off += (size_t)N_NODES * CIN * 2;
    unsigned short* t2u = (unsigned short*)(ws + off); off += (size_t)N_NODES * HID * 2;
    unsigned short* h2b = (unsigned short*)(ws + off); off += (size_t)N_NODES * HID * 2;
    unsigned long long* part = (unsigned long long*)t2u; // 16MB <= 16.7MB; dead before k_layer1

    // zero hist + partial (contiguous)
    hipMemsetAsync(hist, 0, (size_t)NBUCK * HBLK * 4 + 4096, stream);

    k_wswiz  <<<8, 256, 0, stream>>>(W1, W2, wf1, wf2);
    k_hist   <<<HBLK, 256, 0, stream>>>(dst, hist);
    k_scan1  <<<NBUCK * HBLK / 512, 256, 0, stream>>>(hist, hist, partial);
    k_scan2  <<<1, 256, 0, stream>>>(partial);
    k_scatter<<<HBLK, 256, 0, stream>>>(src, dst, ea, hist, partial, part);
    k_bucket <<<NBUCK, 256, 0, stream>>>(part, hist, partial, csr, rowptr, counts,
                                         dis, x, xb2);
    k_layer1 <<<N_NODES / 32, 256, 0, stream>>>(xb2, csr, rowptr, counts, dis,
                                                wf1, wf2, b1, t2u);
    k_agg2   <<<N_NODES / 32, 256, 0, stream>>>((const uint2*)t2u, csr, rowptr,
                                                counts, dis, b2, h2b);
    k_fc     <<<NGRAPH, 256, 0, stream>>>(h2b, Wfc, bfc, out);
}

// Round 10
// 256.913 us; speedup vs baseline: 1.0204x; 1.0204x over previous
//
#include <hip/hip_runtime.h>

#define N_NODES 131072
#define NE      2097152
#define CIN     64
#define HID     64
#define H2X     128   // 2*HID
#define NODESG  128   // nodes per graph
#define NGRAPH  1024
#define NCLS    4

#define NBUCK   256   // buckets = dst>>9
#define NPB     512   // nodes per bucket
#define HBLK    1024  // histogram blocks
#define EPB     2048  // edges per histogram/scatter block
#define STAGE_CAP 10240  // LDS edge stage per bucket (Poisson(8192) max ~8.5K)
#define DEGSC   1048576.0f   // 2^20 fixed-point for LDS deg accumulation
#define DEGMASK ((1ull << 40) - 1)

typedef short bf16x8 __attribute__((ext_vector_type(8)));
typedef float f32x4  __attribute__((ext_vector_type(4)));

// bf16 helpers (RNE; inputs finite)
__device__ __forceinline__ unsigned short f2b(float f) {
    unsigned int u = __float_as_uint(f);
    return (unsigned short)((u + 0x7fffu + ((u >> 16) & 1u)) >> 16);
}
__device__ __forceinline__ unsigned int pack2(float a, float b) {
    return (unsigned int)f2b(a) | ((unsigned int)f2b(b) << 16);
}
__device__ __forceinline__ float blo(unsigned u) { return __uint_as_float(u << 16); }
__device__ __forceinline__ float bhi(unsigned u) { return __uint_as_float(u & 0xffff0000u); }

// ---------------- hist (blocks 0..1023) + W-swizzle (blocks 1024..1031) ----------
// r10: launch-graph consolidation. k_wswiz's 8 blocks ride along with k_hist
// (disjoint inputs/outputs); removes one serial launch boundary. The old
// memset launch is deleted too: k_hist writes EVERY hist entry, k_scan1
// writes every partial entry, so zeroing was dead work.

__global__ __launch_bounds__(256) void k_hist(
        const int* __restrict__ dst, int* __restrict__ hist,
        const float* __restrict__ W1, const float* __restrict__ W2,
        unsigned short* __restrict__ wf1, unsigned short* __restrict__ wf2) {
    int t = threadIdx.x;
    int b = blockIdx.x;
    if (b >= HBLK) {
        int bb = b - HBLK;                        // 0..7: weight swizzle
        int idx = (bb & 3) * 256 + t;             // 0..1023
        if (bb < 4) {
            // W1: 16 frags (kt<2, nt<8) x 64 lanes
            int kt = idx >> 9, nt = (idx >> 6) & 7, l = idx & 63;
            int lm = l & 15, lq = l >> 4;
            unsigned pk[4];
            #pragma unroll
            for (int jp = 0; jp < 4; ++jp) {
                float w0 = W1[(kt*32 + lq*8 + 2*jp)     * H2X + nt*16 + lm];
                float w1 = W1[(kt*32 + lq*8 + 2*jp + 1) * H2X + nt*16 + lm];
                pk[jp] = pack2(w0, w1);
            }
            *(uint4*)&wf1[idx * 8] = make_uint4(pk[0], pk[1], pk[2], pk[3]);
        } else {
            // W2: 16 frags (kt<4, nt<4) x 64 lanes
            int kt = idx >> 8, nt = (idx >> 6) & 3, l = idx & 63;
            int lm = l & 15, lq = l >> 4;
            unsigned pk[4];
            #pragma unroll
            for (int jp = 0; jp < 4; ++jp) {
                float w0 = W2[(kt*32 + lq*8 + 2*jp)     * HID + nt*16 + lm];
                float w1 = W2[(kt*32 + lq*8 + 2*jp + 1) * HID + nt*16 + lm];
                pk[jp] = pack2(w0, w1);
            }
            *(uint4*)&wf2[idx * 8] = make_uint4(pk[0], pk[1], pk[2], pk[3]);
        }
        return;
    }
    __shared__ unsigned bh[NBUCK];
    bh[t] = 0;
    __syncthreads();
    int base = b * EPB;
    #pragma unroll
    for (int k = 0; k < EPB / 256; ++k) {
        int d = dst[base + t + 256 * k];
        atomicAdd(&bh[d >> 9], 1u);
    }
    __syncthreads();
    hist[t * HBLK + b] = (int)bh[t];   // bucket-major layout
}

__global__ void k_scan1(const int* __restrict__ in, int* __restrict__ out,
                        int* __restrict__ partial) {
    __shared__ int sd[256];
    int t = threadIdx.x;
    int base = blockIdx.x * 512;
    int c0 = in[base + 2*t];
    int c1 = in[base + 2*t + 1];
    int loc = c0 + c1;
    sd[t] = loc;
    __syncthreads();
    for (int off = 1; off < 256; off <<= 1) {
        int v = (t >= off) ? sd[t - off] : 0;
        __syncthreads();
        sd[t] += v;
        __syncthreads();
    }
    int excl = sd[t] - loc;
    out[base + 2*t]     = excl;
    out[base + 2*t + 1] = excl + c0;
    if (t == 255) partial[blockIdx.x] = sd[t];
}

// local 512-entry exclusive scan of partial[] into sp[] (one per consumer
// block; replaces the former 1-block k_scan2 kernel, which serialized the
// whole device behind a single workgroup).
#define LOCAL_PSCAN(partial, sp, sd, t)                                        \
    {                                                                          \
        int p0 = partial[2*t], p1 = partial[2*t + 1];                          \
        int loc = p0 + p1;                                                     \
        sd[t] = loc;                                                           \
        __syncthreads();                                                       \
        for (int off = 1; off < 256; off <<= 1) {                              \
            int v = (t >= off) ? sd[t - off] : 0;                              \
            __syncthreads();                                                   \
            sd[t] += v;                                                        \
            __syncthreads();                                                   \
        }                                                                      \
        int excl = sd[t] - loc;                                                \
        sp[2*t] = excl; sp[2*t + 1] = excl + p0;                               \
        __syncthreads();                                                       \
    }

// scatter edges into bucket-major order; global base = hist(local scan) + sp
__global__ __launch_bounds__(256) void k_scatter(
        const int* __restrict__ src, const int* __restrict__ dst,
        const float* __restrict__ ew, const int* __restrict__ hist,
        const int* __restrict__ partial, unsigned long long* __restrict__ part) {
    __shared__ unsigned lcur[NBUCK];
    __shared__ int sp[512];
    __shared__ int sd[256];
    int t = threadIdx.x;
    LOCAL_PSCAN(partial, sp, sd, t);
    int gi = t * HBLK + blockIdx.x;
    lcur[t] = (unsigned)(hist[gi] + sp[gi >> 9]);
    __syncthreads();
    int base = blockIdx.x * EPB;
    #pragma unroll
    for (int k = 0; k < EPB / 256; ++k) {
        int e = base + t + 256 * k;
        int s = src[e], d = dst[e];
        unsigned w = __float_as_uint(ew[e]);
        unsigned p = atomicAdd(&lcur[d >> 9], 1u);
        part[p] = ((unsigned long long)w << 32) |
                  ((unsigned long long)(unsigned)(d & 511) << 17) |
                  (unsigned long long)(unsigned)s;
    }
}

// one block per bucket: single global pass (LDS edge stage, overflow-guarded),
// count+deg, LDS scan -> rowptr, rank-scatter to csr from LDS, fused xcast.
__global__ __launch_bounds__(256) void k_bucket(
        const unsigned long long* __restrict__ part, const int* __restrict__ hist,
        const int* __restrict__ partial, int2* __restrict__ csr,
        int* __restrict__ rowptr, int* __restrict__ counts, float* __restrict__ dis,
        const float* __restrict__ x, uint2* __restrict__ xb2) {
    __shared__ unsigned long long stage[STAGE_CAP];  // 80KB edge stage
    __shared__ unsigned long long dc[NPB];   // count<<40 | deg-fixed-point
    __shared__ unsigned cnt2[NPB];
    __shared__ int rp[NPB];
    __shared__ int sd[256];
    __shared__ int sp[512];
    __shared__ float sdis[NPB];
    int t = threadIdx.x, b = blockIdx.x;
    dc[t] = 0; dc[t + 256] = 0;
    cnt2[t] = 0; cnt2[t + 256] = 0;
    LOCAL_PSCAN(partial, sp, sd, t);
    int start = hist[b * HBLK] + sp[2 * b];
    int end   = (b == NBUCK - 1) ? NE : (hist[(b + 1) * HBLK] + sp[2 * (b + 1)]);
    __syncthreads();

    for (int j = start + t; j < end; j += 256) {
        unsigned long long p = part[j];
        int loc = j - start;
        if (loc < STAGE_CAP) stage[loc] = p;     // overflow: re-read in pass 2
        unsigned dl = (unsigned)(p >> 17) & 511u;
        float w = __uint_as_float((unsigned)(p >> 32));
        atomicAdd(&dc[dl], (1ull << 40) | (unsigned long long)(unsigned)(w * DEGSC));
    }
    __syncthreads();

    unsigned long long d0 = dc[2*t], d1 = dc[2*t + 1];
    int c0 = (int)(d0 >> 40), c1 = (int)(d1 >> 40);
    int loc = c0 + c1;
    sd[t] = loc;
    __syncthreads();
    for (int off = 1; off < 256; off <<= 1) {
        int v = (t >= off) ? sd[t - off] : 0;
        __syncthreads();
        sd[t] += v;
        __syncthreads();
    }
    int excl = sd[t] - loc;
    rp[2*t] = excl; rp[2*t + 1] = excl + c0;

    int n0 = b * NPB;
    rowptr[n0 + 2*t]     = start + excl;
    rowptr[n0 + 2*t + 1] = start + excl + c0;
    counts[n0 + 2*t]     = c0;
    counts[n0 + 2*t + 1] = c1;
    float dg0 = (float)(d0 & DEGMASK) * (1.0f / DEGSC);
    float dg1 = (float)(d1 & DEGMASK) * (1.0f / DEGSC);
    float di0 = rsqrtf(dg0 + 1.0f);
    float di1 = rsqrtf(dg1 + 1.0f);
    dis[n0 + 2*t]     = di0;
    dis[n0 + 2*t + 1] = di1;
    sdis[2*t]     = di0;
    sdis[2*t + 1] = di1;
    __syncthreads();

    for (int j = start + t; j < end; j += 256) {
        int lo = j - start;
        unsigned long long p = (lo < STAGE_CAP) ? stage[lo] : part[j];
        unsigned dl = (unsigned)(p >> 17) & 511u;
        int s = (int)(p & 0x1ffffu);
        unsigned r = atomicAdd(&cnt2[dl], 1u);
        csr[start + rp[dl] + (int)r] = make_int2(s, (int)(unsigned)(p >> 32)); // raw ew
    }

    // fused xcast: xb2[node] = bf16(dis[node] * x[node]) for this bucket's nodes
    const float4* x4 = (const float4*)x + (size_t)n0 * 16;
    uint2* y2 = xb2 + (size_t)n0 * 16;
    #pragma unroll 4
    for (int i = t; i < NPB * 16; i += 256) {
        float d = sdis[i >> 4];
        float4 v = x4[i];
        y2[i] = make_uint2(pack2(d * v.x, d * v.y), pack2(d * v.z, d * v.w));
    }
}

// ---- shared gather-pair macro body: quarter-wave (16 lanes/edge, 4 ch/lane) ----
// r8 CONCLUSION (final for the gathers): streaming body @ bounds(256,8) fits
// the 8-wave tier (VGPR 32, no spill); occupancy 42->65% bought only -3% =>
// gather is bandwidth-bound at ~2.7 TB/s fetch on compulsory traffic
// (123MB = Poisson floor). DO NOT TOUCH the gather kernels.

#define GATHER_PAIR(TAB, pA, pB, nA, nB, cmA, cmB, a0,a1,a2,a3, b0,b1,b2,b3, vSA, vSB) \
    {                                                                                  \
        int   sA0 = __shfl(pA.x, qid),      sA1 = __shfl(pA.x, qid + 4);               \
        int   sA2 = __shfl(pA.x, qid + 8),  sA3 = __shfl(pA.x, qid + 12);              \
        float fA0 = __int_as_float(__shfl(pA.y, qid));                                 \
        float fA1 = __int_as_float(__shfl(pA.y, qid + 4));                             \
        float fA2 = __int_as_float(__shfl(pA.y, qid + 8));                             \
        float fA3 = __int_as_float(__shfl(pA.y, qid + 12));                            \
        int   sB0 = __shfl(pB.x, qid),      sB1 = __shfl(pB.x, qid + 4);               \
        int   sB2 = __shfl(pB.x, qid + 8),  sB3 = __shfl(pB.x, qid + 12);              \
        float fB0 = __int_as_float(__shfl(pB.y, qid));                                 \
        float fB1 = __int_as_float(__shfl(pB.y, qid + 4));                             \
        float fB2 = __int_as_float(__shfl(pB.y, qid + 8));                             \
        float fB3 = __int_as_float(__shfl(pB.y, qid + 12));                            \
        uint2 vA0 = TAB[((unsigned)sA0 << 4) | ql];                                    \
        uint2 vA1 = TAB[((unsigned)sA1 << 4) | ql];                                    \
        uint2 vA2 = TAB[((unsigned)sA2 << 4) | ql];                                    \
        uint2 vA3 = TAB[((unsigned)sA3 << 4) | ql];                                    \
        uint2 vB0 = TAB[((unsigned)sB0 << 4) | ql];                                    \
        uint2 vB1 = TAB[((unsigned)sB1 << 4) | ql];                                    \
        uint2 vB2 = TAB[((unsigned)sB2 << 4) | ql];                                    \
        uint2 vB3 = TAB[((unsigned)sB3 << 4) | ql];                                    \
        vSA = TAB[((unsigned)nA << 4) | ql];                                           \
        vSB = TAB[((unsigned)nB << 4) | ql];                                           \
        a0 = fmaf(fA0, blo(vA0.x), a0); a1 = fmaf(fA0, bhi(vA0.x), a1);                \
        a2 = fmaf(fA0, blo(vA0.y), a2); a3 = fmaf(fA0, bhi(vA0.y), a3);                \
        a0 = fmaf(fA1, blo(vA1.x), a0); a1 = fmaf(fA1, bhi(vA1.x), a1);                \
        a2 = fmaf(fA1, blo(vA1.y), a2); a3 = fmaf(fA1, bhi(vA1.y), a3);                \
        a0 = fmaf(fA2, blo(vA2.x), a0); a1 = fmaf(fA2, bhi(vA2.x), a1);                \
        a2 = fmaf(fA2, blo(vA2.y), a2); a3 = fmaf(fA2, bhi(vA2.y), a3);                \
        a0 = fmaf(fA3, blo(vA3.x), a0); a1 = fmaf(fA3, bhi(vA3.x), a1);                \
        a2 = fmaf(fA3, blo(vA3.y), a2); a3 = fmaf(fA3, bhi(vA3.y), a3);                \
        b0 = fmaf(fB0, blo(vB0.x), b0); b1 = fmaf(fB0, bhi(vB0.x), b1);                \
        b2 = fmaf(fB0, blo(vB0.y), b2); b3 = fmaf(fB0, bhi(vB0.y), b3);                \
        b0 = fmaf(fB1, blo(vB1.x), b0); b1 = fmaf(fB1, bhi(vB1.x), b1);                \
        b2 = fmaf(fB1, blo(vB1.y), b2); b3 = fmaf(fB1, bhi(vB1.y), b3);                \
        b0 = fmaf(fB2, blo(vB2.x), b0); b1 = fmaf(fB2, bhi(vB2.x), b1);                \
        b2 = fmaf(fB2, blo(vB2.y), b2); b3 = fmaf(fB2, bhi(vB2.y), b3);                \
        b0 = fmaf(fB3, blo(vB3.x), b0); b1 = fmaf(fB3, bhi(vB3.x), b1);                \
        b2 = fmaf(fB3, blo(vB3.y), b2); b3 = fmaf(fB3, bhi(vB3.y), b3);                \
        int tsA = (cmA > 16) ? ((cmA - 13) >> 2) : 0;                                  \
        int tsB = (cmB > 16) ? ((cmB - 13) >> 2) : 0;                                  \
        int tsM = tsA > tsB ? tsA : tsB;                                               \
        if (tsM > 0) {                                                                 \
            int jj0 = 16 + qid;                                                        \
            float tfA = __int_as_float(__shfl(pA.y, jj0));                             \
            float tfB = __int_as_float(__shfl(pB.y, jj0));                             \
            uint2 tvA = TAB[((unsigned)__shfl(pA.x, jj0) << 4) | ql];                  \
            uint2 tvB = TAB[((unsigned)__shfl(pB.x, jj0) << 4) | ql];                  \
            for (int k = 1; k < tsM; ++k) {                                            \
                int jj = 16 + 4 * k + qid;                                             \
                float nfA = __int_as_float(__shfl(pA.y, jj));                          \
                float nfB = __int_as_float(__shfl(pB.y, jj));                          \
                uint2 nvA = TAB[((unsigned)__shfl(pA.x, jj) << 4) | ql];               \
                uint2 nvB = TAB[((unsigned)__shfl(pB.x, jj) << 4) | ql];               \
                a0 = fmaf(tfA, blo(tvA.x), a0); a1 = fmaf(tfA, bhi(tvA.x), a1);        \
                a2 = fmaf(tfA, blo(tvA.y), a2); a3 = fmaf(tfA, bhi(tvA.y), a3);        \
                b0 = fmaf(tfB, blo(tvB.x), b0); b1 = fmaf(tfB, bhi(tvB.x), b1);        \
                b2 = fmaf(tfB, blo(tvB.y), b2); b3 = fmaf(tfB, bhi(tvB.y), b3);        \
                tfA = nfA; tfB = nfB; tvA = nvA; tvB = nvB;                            \
            }                                                                          \
            a0 = fmaf(tfA, blo(tvA.x), a0); a1 = fmaf(tfA, bhi(tvA.x), a1);            \
            a2 = fmaf(tfA, blo(tvA.y), a2); a3 = fmaf(tfA, bhi(tvA.y), a3);            \
            b0 = fmaf(tfB, blo(tvB.x), b0); b1 = fmaf(tfB, bhi(tvB.x), b1);            \
            b2 = fmaf(tfB, blo(tvB.y), b2); b3 = fmaf(tfB, bhi(tvB.y), b3);            \
        }                                                                              \
        a0 += __shfl_xor(a0, 16); a1 += __shfl_xor(a1, 16);                            \
        a2 += __shfl_xor(a2, 16); a3 += __shfl_xor(a3, 16);                            \
        a0 += __shfl_xor(a0, 32); a1 += __shfl_xor(a1, 32);                            \
        a2 += __shfl_xor(a2, 32); a3 += __shfl_xor(a3, 32);                            \
        b0 += __shfl_xor(b0, 16); b1 += __shfl_xor(b1, 16);                            \
        b2 += __shfl_xor(b2, 16); b3 += __shfl_xor(b3, 16);                            \
        b0 += __shfl_xor(b0, 32); b1 += __shfl_xor(b1, 32);                            \
        b2 += __shfl_xor(b2, 32); b3 += __shfl_xor(b3, 32);                            \
    }

// -------- fused layer 1+2-GEMM: t2u = bf16( dis * (relu((A_hat x)W1 + b1)) W2 ) ----

__global__ __launch_bounds__(256, 8) void k_layer1(
        const uint2* __restrict__ xb2, const int2* __restrict__ csr,
        const int* __restrict__ rowptr, const int* __restrict__ counts,
        const float* __restrict__ dis, const unsigned short* __restrict__ wf1,
        const unsigned short* __restrict__ wf2, const float* __restrict__ b1,
        unsigned short* __restrict__ t2u) {
    __shared__ unsigned short smem[32 * 136];     // union: sagg[32][72] then sh1[32][136]
    unsigned short (*sagg_b)[72]  = (unsigned short (*)[72])smem;
    unsigned short (*sh1)[136]    = (unsigned short (*)[136])smem;
    int tid = threadIdx.x;

    int wave = tid >> 6, lane = tid & 63;
    int qid = lane >> 4, ql = lane & 15;
    int n0 = blockIdx.x * 32;
    int nb = n0 + wave * 8;

    #pragma unroll 1
    for (int ip = 0; ip < 8; ip += 2) {
        int nA = nb + ip, nB = nA + 1;
        int cA = counts[nA], cB = counts[nB];
        int rsA = rowptr[nA], rsB = rowptr[nB];
        float dnA = dis[nA], dnB = dis[nB];
        int cmA = cA < 64 ? cA : 64, cmB = cB < 64 ? cB : 64;
        int2 pA = (lane < cmA) ? csr[rsA + lane] : make_int2(0, 0);
        int2 pB = (lane < cmB) ? csr[rsB + lane] : make_int2(0, 0);
        float a0 = 0.f, a1 = 0.f, a2 = 0.f, a3 = 0.f;
        float b0 = 0.f, b1v = 0.f, b2v = 0.f, b3 = 0.f;
        uint2 vSA, vSB;
        GATHER_PAIR(xb2, pA, pB, nA, nB, cmA, cmB,
                    a0, a1, a2, a3, b0, b1v, b2v, b3, vSA, vSB);
        if (cA > 64) {                             // essentially never
            for (int jj = 64; jj < cA; ++jj) {
                int2 p = csr[rsA + jj];
                float f = __int_as_float(p.y);
                uint2 v = xb2[((unsigned)p.x << 4) | ql];
                if (qid == 0) {
                    a0 += f * blo(v.x); a1 += f * bhi(v.x);
                    a2 += f * blo(v.y); a3 += f * bhi(v.y);
                }
            }
        }
        if (cB > 64) {
            for (int jj = 64; jj < cB; ++jj) {
                int2 p = csr[rsB + jj];
                float f = __int_as_float(p.y);
                uint2 v = xb2[((unsigned)p.x << 4) | ql];
                if (qid == 0) {
                    b0 += f * blo(v.x); b1v += f * bhi(v.x);
                    b2v += f * blo(v.y); b3 += f * bhi(v.y);
                }
            }
        }
        if (qid == 0) {
            int m = wave * 8 + ip;
            *(uint2*)&sagg_b[m][ql * 4] =
                make_uint2(pack2(dnA * (a0 + blo(vSA.x)), dnA * (a1 + bhi(vSA.x))),
                           pack2(dnA * (a2 + blo(vSA.y)), dnA * (a3 + bhi(vSA.y))));
            *(uint2*)&sagg_b[m + 1][ql * 4] =
                make_uint2(pack2(dnB * (b0 + blo(vSB.x)), dnB * (b1v + bhi(vSB.x))),
                           pack2(dnB * (b2v + blo(vSB.y)), dnB * (b3 + bhi(vSB.y))));
        }
    }
    __syncthreads();

    // MFMA GEMM 1: agg(32x64) @ W1(64x128) -> relu+bias -> sh1 (bf16)
    int mt = wave & 1, ntb = (wave >> 1) * 4;
    int lm = lane & 15, lq = lane >> 4;
    float bs[4];
    #pragma unroll
    for (int t = 0; t < 4; ++t) bs[t] = b1[(ntb + t) * 16 + lm];   // L1/L2-hot
    bf16x8 af0 = *(const bf16x8*)&sagg_b[mt*16 + lm][lq * 8];
    bf16x8 af1 = *(const bf16x8*)&sagg_b[mt*16 + lm][32 + lq * 8];
    __syncthreads();   // sagg fully read (in regs) before sh1 overwrites the union
    #pragma unroll
    for (int t = 0; t < 4; ++t) {
        int nt = ntb + t;
        bf16x8 bf0 = *(const bf16x8*)&wf1[(nt*64 + lane) * 8];
        bf16x8 bf1 = *(const bf16x8*)&wf1[((8 + nt)*64 + lane) * 8];
        f32x4 acc = {0.f, 0.f, 0.f, 0.f};
        acc = __builtin_amdgcn_mfma_f32_16x16x32_bf16(af0, bf0, acc, 0, 0, 0);
        acc = __builtin_amdgcn_mfma_f32_16x16x32_bf16(af1, bf1, acc, 0, 0, 0);
        int ch = nt*16 + lm;
        float bias = bs[t];
        #pragma unroll
        for (int r = 0; r < 4; ++r)
            sh1[mt*16 + lq*4 + r][ch] = f2b(fmaxf(acc[r] + bias, 0.f));
    }
    __syncthreads();

    // MFMA GEMM 2: sh1(32x128) @ W2(128x64) -> t2u = bf16(dis * .)
    #pragma unroll
    for (int ti = 0; ti < 2; ++ti) {
        int t = wave * 2 + ti;                    // 8 tiles: 2 mt x 4 nt
        int mt2 = t & 1, nt2 = t >> 1;
        f32x4 acc = {0.f, 0.f, 0.f, 0.f};
        #pragma unroll
        for (int kt = 0; kt < 4; ++kt) {
            bf16x8 af = *(const bf16x8*)&sh1[mt2*16 + lm][kt*32 + lq*8];
            bf16x8 bf = *(const bf16x8*)&wf2[((kt*4 + nt2)*64 + lane) * 8];
            acc = __builtin_amdgcn_mfma_f32_16x16x32_bf16(af, bf, acc, 0, 0, 0);
        }
        int ch = nt2*16 + lm;
        #pragma unroll
        for (int r = 0; r < 4; ++r) {
            int node = n0 + mt2*16 + lq*4 + r;
            t2u[(size_t)node * HID + ch] = f2b(dis[node] * acc[r]);
        }
    }
}

// ---------------- layer 2 aggregation: h2b = bf16(relu( dn*(sum ew*t2y + t2y[n]) + b2 ))
// NOTE (r12 lesson): do NOT fuse load-dependent epilogues (e.g. FC Wfc loads)
// into this loop's tail — added load->use chains under quarter-lane divergence
// cost +23us. Stores are fine; loads are not.

__global__ __launch_bounds__(256, 8) void k_agg2(
        const uint2* __restrict__ t2y, const int2* __restrict__ csr,
        const int* __restrict__ rowptr, const int* __restrict__ counts,
        const float* __restrict__ dis, const float* __restrict__ b2,
        unsigned short* __restrict__ h2b) {
    int tid = threadIdx.x;
    int wave = tid >> 6, lane = tid & 63;
    int qid = lane >> 4, ql = lane & 15;
    float4 bb = *(const float4*)&b2[ql * 4];
    int n0 = blockIdx.x * 32;
    int nb = n0 + wave * 8;

    #pragma unroll 1
    for (int ip = 0; ip < 8; ip += 2) {
        int nA = nb + ip, nB = nA + 1;
        int cA = counts[nA], cB = counts[nB];
        int rsA = rowptr[nA], rsB = rowptr[nB];
        float dnA = dis[nA], dnB = dis[nB];
        int cmA = cA < 64 ? cA : 64, cmB = cB < 64 ? cB : 64;
        int2 pA = (lane < cmA) ? csr[rsA + lane] : make_int2(0, 0);
        int2 pB = (lane < cmB) ? csr[rsB + lane] : make_int2(0, 0);
        float a0 = 0.f, a1 = 0.f, a2 = 0.f, a3 = 0.f;
        float b0 = 0.f, b1v = 0.f, b2v = 0.f, b3 = 0.f;
        uint2 vSA, vSB;
        GATHER_PAIR(t2y, pA, pB, nA, nB, cmA, cmB,
                    a0, a1, a2, a3, b0, b1v, b2v, b3, vSA, vSB);
        if (cA > 64) {
            for (int jj = 64; jj < cA; ++jj) {
                int2 p = csr[rsA + jj];
                float f = __int_as_float(p.y);
                uint2 v = t2y[((unsigned)p.x << 4) | ql];
                if (qid == 0) {
                    a0 += f * blo(v.x); a1 += f * bhi(v.x);
                    a2 += f * blo(v.y); a3 += f * bhi(v.y);
                }
            }
        }
        if (cB > 64) {
            for (int jj = 64; jj < cB; ++jj) {
                int2 p = csr[rsB + jj];
                float f = __int_as_float(p.y);
                uint2 v = t2y[((unsigned)p.x << 4) | ql];
                if (qid == 0) {
                    b0 += f * blo(v.x); b1v += f * bhi(v.x);
                    b2v += f * blo(v.y); b3 += f * bhi(v.y);
                }
            }
        }
        if (qid == 0) {
            float oa0 = fmaxf(fmaf(dnA, a0 + blo(vSA.x), bb.x), 0.f);
            float oa1 = fmaxf(fmaf(dnA, a1 + bhi(vSA.x), bb.y), 0.f);
            float oa2 = fmaxf(fmaf(dnA, a2 + blo(vSA.y), bb.z), 0.f);
            float oa3 = fmaxf(fmaf(dnA, a3 + bhi(vSA.y), bb.w), 0.f);
            float ob0 = fmaxf(fmaf(dnB, b0 + blo(vSB.x), bb.x), 0.f);
            float ob1 = fmaxf(fmaf(dnB, b1v + bhi(vSB.x), bb.y), 0.f);
            float ob2 = fmaxf(fmaf(dnB, b2v + blo(vSB.y), bb.z), 0.f);
            float ob3 = fmaxf(fmaf(dnB, b3 + bhi(vSB.y), bb.w), 0.f);
            *(uint2*)&h2b[((unsigned)nA << 6) | (ql * 4)] =
                make_uint2(pack2(oa0, oa1), pack2(oa2, oa3));
            *(uint2*)&h2b[((unsigned)nB << 6) | (ql * 4)] =
                make_uint2(pack2(ob0, ob1), pack2(ob2, ob3));
        }
    }
}

// ---------------- FC + softmax (bf16 h2) ----------------
// r10: per-wave shfl reduction (1 barrier) replaces 8-level LDS tree (9 barriers).

__global__ __launch_bounds__(256) void k_fc(
        const unsigned short* __restrict__ h2b, const float* __restrict__ Wfc,
        const float* __restrict__ bfc, float* __restrict__ out) {
    __shared__ float4 red[4];
    int b = blockIdx.x, t = threadIdx.x;
    int wave = t >> 6, lane = t & 63;
    const uint2* hrow = (const uint2*)(h2b + (size_t)b * (HID * NODESG));
    const float4* W4 = (const float4*)Wfc;
    float4 a = make_float4(0.f, 0.f, 0.f, 0.f);
    #pragma unroll
    for (int j = 0; j < 8; ++j) {
        int i = j * 256 + t;                    // uint2 index: 4 channels
        uint2 hv = hrow[i];
        float h0 = blo(hv.x), h1 = bhi(hv.x), h2v = blo(hv.y), h3 = bhi(hv.y);
        float4 w0 = W4[i * 4 + 0];
        float4 w1 = W4[i * 4 + 1];
        float4 w2 = W4[i * 4 + 2];
        float4 w3 = W4[i * 4 + 3];
        a.x = fmaf(h0, w0.x, a.x); a.y = fmaf(h0, w0.y, a.y);
        a.z = fmaf(h0, w0.z, a.z); a.w = fmaf(h0, w0.w, a.w);
        a.x = fmaf(h1, w1.x, a.x); a.y = fmaf(h1, w1.y, a.y);
        a.z = fmaf(h1, w1.z, a.z); a.w = fmaf(h1, w1.w, a.w);
        a.x = fmaf(h2v, w2.x, a.x); a.y = fmaf(h2v, w2.y, a.y);
        a.z = fmaf(h2v, w2.z, a.z); a.w = fmaf(h2v, w2.w, a.w);
        a.x = fmaf(h3, w3.x, a.x); a.y = fmaf(h3, w3.y, a.y);
        a.z = fmaf(h3, w3.z, a.z); a.w = fmaf(h3, w3.w, a.w);
    }
    #pragma unroll
    for (int off = 1; off < 64; off <<= 1) {
        a.x += __shfl_xor(a.x, off);
        a.y += __shfl_xor(a.y, off);
        a.z += __shfl_xor(a.z, off);
        a.w += __shfl_xor(a.w, off);
    }
    if (lane == 0) red[wave] = a;
    __syncthreads();
    if (t == 0) {
        float l0 = red[0].x + red[1].x + red[2].x + red[3].x + bfc[0];
        float l1 = red[0].y + red[1].y + red[2].y + red[3].y + bfc[1];
        float l2 = red[0].z + red[1].z + red[2].z + red[3].z + bfc[2];
        float l3 = red[0].w + red[1].w + red[2].w + red[3].w + bfc[3];
        float mx = fmaxf(fmaxf(l0, l1), fmaxf(l2, l3));
        float e0 = expf(l0 - mx), e1 = expf(l1 - mx);
        float e2 = expf(l2 - mx), e3 = expf(l3 - mx);
        float inv = 1.f / (e0 + e1 + e2 + e3);
        float4 o = make_float4(e0 * inv, e1 * inv, e2 * inv, e3 * inv);
        *(float4*)&out[(size_t)b * 4] = o;
    }
}

// ---------------- launch ----------------
// r10 launch graph: 7 kernels (was 10): memset deleted (hist/partial fully
// overwritten), wswiz folded into hist, scan2 folded into consumers.

extern "C" void kernel_launch(void* const* d_in, const int* in_sizes, int n_in,
                              void* d_out, int out_size, void* d_ws, size_t ws_size,
                              hipStream_t stream) {
    const float* x   = (const float*)d_in[0];
    const int*   ei  = (const int*)  d_in[1];
    const float* ea  = (const float*)d_in[2];
    const float* W1  = (const float*)d_in[3];
    const float* b1  = (const float*)d_in[4];
    const float* W2  = (const float*)d_in[5];
    const float* b2  = (const float*)d_in[6];
    const float* Wfc = (const float*)d_in[7];
    const float* bfc = (const float*)d_in[8];
    float* out = (float*)d_out;
    const int* src = ei;
    const int* dst = ei + NE;

    char* ws = (char*)d_ws;
    size_t off = 0;
    int*   hist   = (int*)  (ws + off); off += (size_t)NBUCK * HBLK * 4;  // 1 MB
    int*   partial= (int*)  (ws + off); off += 4096;
    int*   counts = (int*)  (ws + off); off += (size_t)N_NODES * 4;
    int*   rowptr = (int*)  (ws + off); off += (size_t)N_NODES * 4;
    float* dis    = (float*)(ws + off); off += (size_t)N_NODES * 4;
    unsigned short* wf1 = (unsigned short*)(ws + off); off += 8192 * 2;   // 16 KB
    unsigned short* wf2 = (unsigned short*)(ws + off); off += 8192 * 2;   // 16 KB
    int2*  csr    = (int2*) (ws + off); off += (size_t)NE * 8;
    uint2* xb2    = (uint2*)(ws + off); off += (size_t)N_NODES * CIN * 2;
    unsigned short* t2u = (unsigned short*)(ws + off); off += (size_t)N_NODES * HID * 2;
    unsigned short* h2b = (unsigned short*)(ws + off); off += (size_t)N_NODES * HID * 2;
    unsigned long long* part = (unsigned long long*)t2u; // 16MB <= 16.7MB; dead before k_layer1

    k_hist   <<<HBLK + 8, 256, 0, stream>>>(dst, hist, W1, W2, wf1, wf2);
    k_scan1  <<<NBUCK * HBLK / 512, 256, 0, stream>>>(hist, hist, partial);
    k_scatter<<<HBLK, 256, 0, stream>>>(src, dst, ea, hist, partial, part);
    k_bucket <<<NBUCK, 256, 0, stream>>>(part, hist, partial, csr, rowptr, counts,
                                         dis, x, xb2);
    k_layer1 <<<N_NODES / 32, 256, 0, stream>>>(xb2, csr, rowptr, counts, dis,
                                                wf1, wf2, b1, t2u);
    k_agg2   <<<N_NODES / 32, 256, 0, stream>>>((const uint2*)t2u, csr, rowptr,
                                                counts, dis, b2, h2b);
    k_fc     <<<NGRAPH, 256, 0, stream>>>(h2b, Wfc, bfc, out);
}

// Round 11
// 254.910 us; speedup vs baseline: 1.0284x; 1.0079x over previous
//
#include <hip/hip_runtime.h>

#define N_NODES 131072
#define NE      2097152
#define CIN     64
#define HID     64
#define H2X     128   // 2*HID
#define NODESG  128   // nodes per graph
#define NGRAPH  1024
#define NCLS    4

#define NBUCK   256   // buckets = dst>>9
#define NPB     512   // nodes per bucket
#define HBLK    1024  // histogram blocks
#define EPB     2048  // edges per histogram/scatter block
#define STAGE_CAP 10240  // LDS edge stage per bucket (Poisson(8192) max ~8.5K)
#define DEGSC   1048576.0f   // 2^20 fixed-point for LDS deg accumulation
#define DEGMASK ((1ull << 40) - 1)

typedef short bf16x8 __attribute__((ext_vector_type(8)));
typedef float f32x4  __attribute__((ext_vector_type(4)));

// bf16 helpers (RNE; inputs finite)
__device__ __forceinline__ unsigned short f2b(float f) {
    unsigned int u = __float_as_uint(f);
    return (unsigned short)((u + 0x7fffu + ((u >> 16) & 1u)) >> 16);
}
__device__ __forceinline__ unsigned int pack2(float a, float b) {
    return (unsigned int)f2b(a) | ((unsigned int)f2b(b) << 16);
}
__device__ __forceinline__ float blo(unsigned u) { return __uint_as_float(u << 16); }
__device__ __forceinline__ float bhi(unsigned u) { return __uint_as_float(u & 0xffff0000u); }

// ---------------- hist (blocks 0..1023) + W-swizzle (blocks 1024..1031) ----------

__global__ __launch_bounds__(256) void k_hist(
        const int* __restrict__ dst, int* __restrict__ hist,
        const float* __restrict__ W1, const float* __restrict__ W2,
        unsigned short* __restrict__ wf1, unsigned short* __restrict__ wf2) {
    int t = threadIdx.x;
    int b = blockIdx.x;
    if (b >= HBLK) {
        int bb = b - HBLK;                        // 0..7: weight swizzle
        int idx = (bb & 3) * 256 + t;             // 0..1023
        if (bb < 4) {
            // W1: 16 frags (kt<2, nt<8) x 64 lanes
            int kt = idx >> 9, nt = (idx >> 6) & 7, l = idx & 63;
            int lm = l & 15, lq = l >> 4;
            unsigned pk[4];
            #pragma unroll
            for (int jp = 0; jp < 4; ++jp) {
                float w0 = W1[(kt*32 + lq*8 + 2*jp)     * H2X + nt*16 + lm];
                float w1 = W1[(kt*32 + lq*8 + 2*jp + 1) * H2X + nt*16 + lm];
                pk[jp] = pack2(w0, w1);
            }
            *(uint4*)&wf1[idx * 8] = make_uint4(pk[0], pk[1], pk[2], pk[3]);
        } else {
            // W2: 16 frags (kt<4, nt<4) x 64 lanes
            int kt = idx >> 8, nt = (idx >> 6) & 3, l = idx & 63;
            int lm = l & 15, lq = l >> 4;
            unsigned pk[4];
            #pragma unroll
            for (int jp = 0; jp < 4; ++jp) {
                float w0 = W2[(kt*32 + lq*8 + 2*jp)     * HID + nt*16 + lm];
                float w1 = W2[(kt*32 + lq*8 + 2*jp + 1) * HID + nt*16 + lm];
                pk[jp] = pack2(w0, w1);
            }
            *(uint4*)&wf2[idx * 8] = make_uint4(pk[0], pk[1], pk[2], pk[3]);
        }
        return;
    }
    __shared__ unsigned bh[NBUCK];
    bh[t] = 0;
    __syncthreads();
    int base = b * EPB;
    #pragma unroll
    for (int k = 0; k < EPB / 256; ++k) {
        int d = dst[base + t + 256 * k];
        atomicAdd(&bh[d >> 9], 1u);
    }
    __syncthreads();
    hist[t * HBLK + b] = (int)bh[t];   // bucket-major layout
}

__global__ void k_scan1(const int* __restrict__ in, int* __restrict__ out,
                        int* __restrict__ partial) {
    __shared__ int sd[256];
    int t = threadIdx.x;
    int base = blockIdx.x * 512;
    int c0 = in[base + 2*t];
    int c1 = in[base + 2*t + 1];
    int loc = c0 + c1;
    sd[t] = loc;
    __syncthreads();
    for (int off = 1; off < 256; off <<= 1) {
        int v = (t >= off) ? sd[t - off] : 0;
        __syncthreads();
        sd[t] += v;
        __syncthreads();
    }
    int excl = sd[t] - loc;
    out[base + 2*t]     = excl;
    out[base + 2*t + 1] = excl + c0;
    if (t == 255) partial[blockIdx.x] = sd[t];
}

// local 512-entry exclusive scan of partial[] into sp[]; thread-count-agnostic
// (work gated to t<256, barriers uniform) so 256- and 1024-thread blocks share it.
#define LOCAL_PSCAN(partial, sp, sd, t)                                        \
    {                                                                          \
        int p0_ = 0, loc_ = 0;                                                 \
        if (t < 256) {                                                         \
            p0_ = partial[2*t];                                                \
            int p1_ = partial[2*t + 1];                                        \
            loc_ = p0_ + p1_;                                                  \
            sd[t] = loc_;                                                      \
        }                                                                      \
        __syncthreads();                                                       \
        for (int off = 1; off < 256; off <<= 1) {                              \
            int v = (t >= off && t < 256) ? sd[t - off] : 0;                   \
            __syncthreads();                                                   \
            if (t < 256) sd[t] += v;                                           \
            __syncthreads();                                                   \
        }                                                                      \
        if (t < 256) {                                                         \
            int excl_ = sd[t] - loc_;                                          \
            sp[2*t] = excl_; sp[2*t + 1] = excl_ + p0_;                        \
        }                                                                      \
        __syncthreads();                                                       \
    }

// scatter edges into bucket-major order; global base = hist(local scan) + sp
__global__ __launch_bounds__(256) void k_scatter(
        const int* __restrict__ src, const int* __restrict__ dst,
        const float* __restrict__ ew, const int* __restrict__ hist,
        const int* __restrict__ partial, unsigned long long* __restrict__ part) {
    __shared__ unsigned lcur[NBUCK];
    __shared__ int sp[512];
    __shared__ int sd[256];
    int t = threadIdx.x;
    LOCAL_PSCAN(partial, sp, sd, t);
    int gi = t * HBLK + blockIdx.x;
    lcur[t] = (unsigned)(hist[gi] + sp[gi >> 9]);
    __syncthreads();
    int base = blockIdx.x * EPB;
    #pragma unroll
    for (int k = 0; k < EPB / 256; ++k) {
        int e = base + t + 256 * k;
        int s = src[e], d = dst[e];
        unsigned w = __float_as_uint(ew[e]);
        unsigned p = atomicAdd(&lcur[d >> 9], 1u);
        part[p] = ((unsigned long long)w << 32) |
                  ((unsigned long long)(unsigned)(d & 511) << 17) |
                  (unsigned long long)(unsigned)s;
    }
}

// one block per bucket. r11: 1024 threads/block (was 256). The grid is only
// 256 blocks = 1 block/CU, and the 93KB LDS stage pins residency to a single
// block -- at 256 threads that was 4 waves/CU (12.5%) for ~80MB of streaming,
// i.e. the kernel was occupancy-starved (and why r9's traffic cut was bench-
// neutral). 1024 threads -> 16 waves/CU, same algorithm; scans gated to t<256.
__global__ __launch_bounds__(1024) void k_bucket(
        const unsigned long long* __restrict__ part, const int* __restrict__ hist,
        const int* __restrict__ partial, int2* __restrict__ csr,
        int* __restrict__ rowptr, int* __restrict__ counts, float* __restrict__ dis,
        const float* __restrict__ x, uint2* __restrict__ xb2) {
    __shared__ unsigned long long stage[STAGE_CAP];  // 80KB edge stage
    __shared__ unsigned long long dc[NPB];   // count<<40 | deg-fixed-point
    __shared__ unsigned cnt2[NPB];
    __shared__ int rp[NPB];
    __shared__ int sd[256];
    __shared__ int sp[512];
    __shared__ float sdis[NPB];
    int t = threadIdx.x, b = blockIdx.x;
    if (t < 256) {
        dc[t] = 0; dc[t + 256] = 0;
        cnt2[t] = 0; cnt2[t + 256] = 0;
    }
    LOCAL_PSCAN(partial, sp, sd, t);
    int start = hist[b * HBLK] + sp[2 * b];
    int end   = (b == NBUCK - 1) ? NE : (hist[(b + 1) * HBLK] + sp[2 * (b + 1)]);

    for (int j = start + t; j < end; j += 1024) {
        unsigned long long p = part[j];
        int loc = j - start;
        if (loc < STAGE_CAP) stage[loc] = p;     // overflow: re-read in pass 2
        unsigned dl = (unsigned)(p >> 17) & 511u;
        float w = __uint_as_float((unsigned)(p >> 32));
        atomicAdd(&dc[dl], (1ull << 40) | (unsigned long long)(unsigned)(w * DEGSC));
    }
    __syncthreads();

    int c0_ = 0, loc_ = 0;
    unsigned long long d0 = 0, d1 = 0;
    if (t < 256) {
        d0 = dc[2*t]; d1 = dc[2*t + 1];
        c0_ = (int)(d0 >> 40);
        int c1_ = (int)(d1 >> 40);
        loc_ = c0_ + c1_;
        sd[t] = loc_;
    }
    __syncthreads();
    for (int off = 1; off < 256; off <<= 1) {
        int v = (t >= off && t < 256) ? sd[t - off] : 0;
        __syncthreads();
        if (t < 256) sd[t] += v;
        __syncthreads();
    }
    if (t < 256) {
        int excl = sd[t] - loc_;
        int c1_ = (int)(d1 >> 40);
        rp[2*t] = excl; rp[2*t + 1] = excl + c0_;
        int n0 = b * NPB;
        rowptr[n0 + 2*t]     = start + excl;
        rowptr[n0 + 2*t + 1] = start + excl + c0_;
        counts[n0 + 2*t]     = c0_;
        counts[n0 + 2*t + 1] = c1_;
        float dg0 = (float)(d0 & DEGMASK) * (1.0f / DEGSC);
        float dg1 = (float)(d1 & DEGMASK) * (1.0f / DEGSC);
        float di0 = rsqrtf(dg0 + 1.0f);
        float di1 = rsqrtf(dg1 + 1.0f);
        dis[n0 + 2*t]     = di0;
        dis[n0 + 2*t + 1] = di1;
        sdis[2*t]     = di0;
        sdis[2*t + 1] = di1;
    }
    __syncthreads();

    for (int j = start + t; j < end; j += 1024) {
        int lo = j - start;
        unsigned long long p = (lo < STAGE_CAP) ? stage[lo] : part[j];
        unsigned dl = (unsigned)(p >> 17) & 511u;
        int s = (int)(p & 0x1ffffu);
        unsigned r = atomicAdd(&cnt2[dl], 1u);
        csr[start + rp[dl] + (int)r] = make_int2(s, (int)(unsigned)(p >> 32)); // raw ew
    }

    // fused xcast: xb2[node] = bf16(dis[node] * x[node]) for this bucket's nodes
    int n0 = b * NPB;
    const float4* x4 = (const float4*)x + (size_t)n0 * 16;
    uint2* y2 = xb2 + (size_t)n0 * 16;
    #pragma unroll 2
    for (int i = t; i < NPB * 16; i += 1024) {
        float d = sdis[i >> 4];
        float4 v = x4[i];
        y2[i] = make_uint2(pack2(d * v.x, d * v.y), pack2(d * v.z, d * v.w));
    }
}

// ---- shared gather-pair macro body: quarter-wave (16 lanes/edge, 4 ch/lane) ----
// r8 CONCLUSION (final for the gathers): streaming body @ bounds(256,8) fits
// the 8-wave tier (VGPR 32, no spill); occupancy 42->65% bought only -3% =>
// gather is bandwidth-bound at ~2.7 TB/s fetch on compulsory traffic
// (123MB = Poisson floor). DO NOT TOUCH the gather kernels.

#define GATHER_PAIR(TAB, pA, pB, nA, nB, cmA, cmB, a0,a1,a2,a3, b0,b1,b2,b3, vSA, vSB) \
    {                                                                                  \
        int   sA0 = __shfl(pA.x, qid),      sA1 = __shfl(pA.x, qid + 4);               \
        int   sA2 = __shfl(pA.x, qid + 8),  sA3 = __shfl(pA.x, qid + 12);              \
        float fA0 = __int_as_float(__shfl(pA.y, qid));                                 \
        float fA1 = __int_as_float(__shfl(pA.y, qid + 4));                             \
        float fA2 = __int_as_float(__shfl(pA.y, qid + 8));                             \
        float fA3 = __int_as_float(__shfl(pA.y, qid + 12));                            \
        int   sB0 = __shfl(pB.x, qid),      sB1 = __shfl(pB.x, qid + 4);               \
        int   sB2 = __shfl(pB.x, qid + 8),  sB3 = __shfl(pB.x, qid + 12);              \
        float fB0 = __int_as_float(__shfl(pB.y, qid));                                 \
        float fB1 = __int_as_float(__shfl(pB.y, qid + 4));                             \
        float fB2 = __int_as_float(__shfl(pB.y, qid + 8));                             \
        float fB3 = __int_as_float(__shfl(pB.y, qid + 12));                            \
        uint2 vA0 = TAB[((unsigned)sA0 << 4) | ql];                                    \
        uint2 vA1 = TAB[((unsigned)sA1 << 4) | ql];                                    \
        uint2 vA2 = TAB[((unsigned)sA2 << 4) | ql];                                    \
        uint2 vA3 = TAB[((unsigned)sA3 << 4) | ql];                                    \
        uint2 vB0 = TAB[((unsigned)sB0 << 4) | ql];                                    \
        uint2 vB1 = TAB[((unsigned)sB1 << 4) | ql];                                    \
        uint2 vB2 = TAB[((unsigned)sB2 << 4) | ql];                                    \
        uint2 vB3 = TAB[((unsigned)sB3 << 4) | ql];                                    \
        vSA = TAB[((unsigned)nA << 4) | ql];                                           \
        vSB = TAB[((unsigned)nB << 4) | ql];                                           \
        a0 = fmaf(fA0, blo(vA0.x), a0); a1 = fmaf(fA0, bhi(vA0.x), a1);                \
        a2 = fmaf(fA0, blo(vA0.y), a2); a3 = fmaf(fA0, bhi(vA0.y), a3);                \
        a0 = fmaf(fA1, blo(vA1.x), a0); a1 = fmaf(fA1, bhi(vA1.x), a1);                \
        a2 = fmaf(fA1, blo(vA1.y), a2); a3 = fmaf(fA1, bhi(vA1.y), a3);                \
        a0 = fmaf(fA2, blo(vA2.x), a0); a1 = fmaf(fA2, bhi(vA2.x), a1);                \
        a2 = fmaf(fA2, blo(vA2.y), a2); a3 = fmaf(fA2, bhi(vA2.y), a3);                \
        a0 = fmaf(fA3, blo(vA3.x), a0); a1 = fmaf(fA3, bhi(vA3.x), a1);                \
        a2 = fmaf(fA3, blo(vA3.y), a2); a3 = fmaf(fA3, bhi(vA3.y), a3);                \
        b0 = fmaf(fB0, blo(vB0.x), b0); b1 = fmaf(fB0, bhi(vB0.x), b1);                \
        b2 = fmaf(fB0, blo(vB0.y), b2); b3 = fmaf(fB0, bhi(vB0.y), b3);                \
        b0 = fmaf(fB1, blo(vB1.x), b0); b1 = fmaf(fB1, bhi(vB1.x), b1);                \
        b2 = fmaf(fB1, blo(vB1.y), b2); b3 = fmaf(fB1, bhi(vB1.y), b3);                \
        b0 = fmaf(fB2, blo(vB2.x), b0); b1 = fmaf(fB2, bhi(vB2.x), b1);                \
        b2 = fmaf(fB2, blo(vB2.y), b2); b3 = fmaf(fB2, bhi(vB2.y), b3);                \
        b0 = fmaf(fB3, blo(vB3.x), b0); b1 = fmaf(fB3, bhi(vB3.x), b1);                \
        b2 = fmaf(fB3, blo(vB3.y), b2); b3 = fmaf(fB3, bhi(vB3.y), b3);                \
        int tsA = (cmA > 16) ? ((cmA - 13) >> 2) : 0;                                  \
        int tsB = (cmB > 16) ? ((cmB - 13) >> 2) : 0;                                  \
        int tsM = tsA > tsB ? tsA : tsB;                                               \
        if (tsM > 0) {                                                                 \
            int jj0 = 16 + qid;                                                        \
            float tfA = __int_as_float(__shfl(pA.y, jj0));                             \
            float tfB = __int_as_float(__shfl(pB.y, jj0));                             \
            uint2 tvA = TAB[((unsigned)__shfl(pA.x, jj0) << 4) | ql];                  \
            uint2 tvB = TAB[((unsigned)__shfl(pB.x, jj0) << 4) | ql];                  \
            for (int k = 1; k < tsM; ++k) {                                            \
                int jj = 16 + 4 * k + qid;                                             \
                float nfA = __int_as_float(__shfl(pA.y, jj));                          \
                float nfB = __int_as_float(__shfl(pB.y, jj));                          \
                uint2 nvA = TAB[((unsigned)__shfl(pA.x, jj) << 4) | ql];               \
                uint2 nvB = TAB[((unsigned)__shfl(pB.x, jj) << 4) | ql];               \
                a0 = fmaf(tfA, blo(tvA.x), a0); a1 = fmaf(tfA, bhi(tvA.x), a1);        \
                a2 = fmaf(tfA, blo(tvA.y), a2); a3 = fmaf(tfA, bhi(tvA.y), a3);        \
                b0 = fmaf(tfB, blo(tvB.x), b0); b1 = fmaf(tfB, bhi(tvB.x), b1);        \
                b2 = fmaf(tfB, blo(tvB.y), b2); b3 = fmaf(tfB, bhi(tvB.y), b3);        \
                tfA = nfA; tfB = nfB; tvA = nvA; tvB = nvB;                            \
            }                                                                          \
            a0 = fmaf(tfA, blo(tvA.x), a0); a1 = fmaf(tfA, bhi(tvA.x), a1);            \
            a2 = fmaf(tfA, blo(tvA.y), a2); a3 = fmaf(tfA, bhi(tvA.y), a3);            \
            b0 = fmaf(tfB, blo(tvB.x), b0); b1 = fmaf(tfB, bhi(tvB.x), b1);            \
            b2 = fmaf(tfB, blo(tvB.y), b2); b3 = fmaf(tfB, bhi(tvB.y), b3);            \
        }                                                                              \
        a0 += __shfl_xor(a0, 16); a1 += __shfl_xor(a1, 16);                            \
        a2 += __shfl_xor(a2, 16); a3 += __shfl_xor(a3, 16);                            \
        a0 += __shfl_xor(a0, 32); a1 += __shfl_xor(a1, 32);                            \
        a2 += __shfl_xor(a2, 32); a3 += __shfl_xor(a3, 32);                            \
        b0 += __shfl_xor(b0, 16); b1 += __shfl_xor(b1, 16);                            \
        b2 += __shfl_xor(b2, 16); b3 += __shfl_xor(b3, 16);                            \
        b0 += __shfl_xor(b0, 32); b1 += __shfl_xor(b1, 32);                            \
        b2 += __shfl_xor(b2, 32); b3 += __shfl_xor(b3, 32);                            \
    }

// -------- fused layer 1+2-GEMM: t2u = bf16( dis * (relu((A_hat x)W1 + b1)) W2 ) ----

__global__ __launch_bounds__(256, 8) void k_layer1(
        const uint2* __restrict__ xb2, const int2* __restrict__ csr,
        const int* __restrict__ rowptr, const int* __restrict__ counts,
        const float* __restrict__ dis, const unsigned short* __restrict__ wf1,
        const unsigned short* __restrict__ wf2, const float* __restrict__ b1,
        unsigned short* __restrict__ t2u) {
    __shared__ unsigned short smem[32 * 136];     // union: sagg[32][72] then sh1[32][136]
    unsigned short (*sagg_b)[72]  = (unsigned short (*)[72])smem;
    unsigned short (*sh1)[136]    = (unsigned short (*)[136])smem;
    int tid = threadIdx.x;

    int wave = tid >> 6, lane = tid & 63;
    int qid = lane >> 4, ql = lane & 15;
    int n0 = blockIdx.x * 32;
    int nb = n0 + wave * 8;

    #pragma unroll 1
    for (int ip = 0; ip < 8; ip += 2) {
        int nA = nb + ip, nB = nA + 1;
        int cA = counts[nA], cB = counts[nB];
        int rsA = rowptr[nA], rsB = rowptr[nB];
        float dnA = dis[nA], dnB = dis[nB];
        int cmA = cA < 64 ? cA : 64, cmB = cB < 64 ? cB : 64;
        int2 pA = (lane < cmA) ? csr[rsA + lane] : make_int2(0, 0);
        int2 pB = (lane < cmB) ? csr[rsB + lane] : make_int2(0, 0);
        float a0 = 0.f, a1 = 0.f, a2 = 0.f, a3 = 0.f;
        float b0 = 0.f, b1v = 0.f, b2v = 0.f, b3 = 0.f;
        uint2 vSA, vSB;
        GATHER_PAIR(xb2, pA, pB, nA, nB, cmA, cmB,
                    a0, a1, a2, a3, b0, b1v, b2v, b3, vSA, vSB);
        if (cA > 64) {                             // essentially never
            for (int jj = 64; jj < cA; ++jj) {
                int2 p = csr[rsA + jj];
                float f = __int_as_float(p.y);
                uint2 v = xb2[((unsigned)p.x << 4) | ql];
                if (qid == 0) {
                    a0 += f * blo(v.x); a1 += f * bhi(v.x);
                    a2 += f * blo(v.y); a3 += f * bhi(v.y);
                }
            }
        }
        if (cB > 64) {
            for (int jj = 64; jj < cB; ++jj) {
                int2 p = csr[rsB + jj];
                float f = __int_as_float(p.y);
                uint2 v = xb2[((unsigned)p.x << 4) | ql];
                if (qid == 0) {
                    b0 += f * blo(v.x); b1v += f * bhi(v.x);
                    b2v += f * blo(v.y); b3 += f * bhi(v.y);
                }
            }
        }
        if (qid == 0) {
            int m = wave * 8 + ip;
            *(uint2*)&sagg_b[m][ql * 4] =
                make_uint2(pack2(dnA * (a0 + blo(vSA.x)), dnA * (a1 + bhi(vSA.x))),
                           pack2(dnA * (a2 + blo(vSA.y)), dnA * (a3 + bhi(vSA.y))));
            *(uint2*)&sagg_b[m + 1][ql * 4] =
                make_uint2(pack2(dnB * (b0 + blo(vSB.x)), dnB * (b1v + bhi(vSB.x))),
                           pack2(dnB * (b2v + blo(vSB.y)), dnB * (b3 + bhi(vSB.y))));
        }
    }
    __syncthreads();

    // MFMA GEMM 1: agg(32x64) @ W1(64x128) -> relu+bias -> sh1 (bf16)
    int mt = wave & 1, ntb = (wave >> 1) * 4;
    int lm = lane & 15, lq = lane >> 4;
    float bs[4];
    #pragma unroll
    for (int t = 0; t < 4; ++t) bs[t] = b1[(ntb + t) * 16 + lm];   // L1/L2-hot
    bf16x8 af0 = *(const bf16x8*)&sagg_b[mt*16 + lm][lq * 8];
    bf16x8 af1 = *(const bf16x8*)&sagg_b[mt*16 + lm][32 + lq * 8];
    __syncthreads();   // sagg fully read (in regs) before sh1 overwrites the union
    #pragma unroll
    for (int t = 0; t < 4; ++t) {
        int nt = ntb + t;
        bf16x8 bf0 = *(const bf16x8*)&wf1[(nt*64 + lane) * 8];
        bf16x8 bf1 = *(const bf16x8*)&wf1[((8 + nt)*64 + lane) * 8];
        f32x4 acc = {0.f, 0.f, 0.f, 0.f};
        acc = __builtin_amdgcn_mfma_f32_16x16x32_bf16(af0, bf0, acc, 0, 0, 0);
        acc = __builtin_amdgcn_mfma_f32_16x16x32_bf16(af1, bf1, acc, 0, 0, 0);
        int ch = nt*16 + lm;
        float bias = bs[t];
        #pragma unroll
        for (int r = 0; r < 4; ++r)
            sh1[mt*16 + lq*4 + r][ch] = f2b(fmaxf(acc[r] + bias, 0.f));
    }
    __syncthreads();

    // MFMA GEMM 2: sh1(32x128) @ W2(128x64) -> t2u = bf16(dis * .)
    #pragma unroll
    for (int ti = 0; ti < 2; ++ti) {
        int t = wave * 2 + ti;                    // 8 tiles: 2 mt x 4 nt
        int mt2 = t & 1, nt2 = t >> 1;
        f32x4 acc = {0.f, 0.f, 0.f, 0.f};
        #pragma unroll
        for (int kt = 0; kt < 4; ++kt) {
            bf16x8 af = *(const bf16x8*)&sh1[mt2*16 + lm][kt*32 + lq*8];
            bf16x8 bf = *(const bf16x8*)&wf2[((kt*4 + nt2)*64 + lane) * 8];
            acc = __builtin_amdgcn_mfma_f32_16x16x32_bf16(af, bf, acc, 0, 0, 0);
        }
        int ch = nt2*16 + lm;
        #pragma unroll
        for (int r = 0; r < 4; ++r) {
            int node = n0 + mt2*16 + lq*4 + r;
            t2u[(size_t)node * HID + ch] = f2b(dis[node] * acc[r]);
        }
    }
}

// ---------------- layer 2 aggregation: h2b = bf16(relu( dn*(sum ew*t2y + t2y[n]) + b2 ))
// NOTE (r12 lesson): do NOT fuse load-dependent epilogues (e.g. FC Wfc loads)
// into this loop's tail — added load->use chains under quarter-lane divergence
// cost +23us. Stores are fine; loads are not.

__global__ __launch_bounds__(256, 8) void k_agg2(
        const uint2* __restrict__ t2y, const int2* __restrict__ csr,
        const int* __restrict__ rowptr, const int* __restrict__ counts,
        const float* __restrict__ dis, const float* __restrict__ b2,
        unsigned short* __restrict__ h2b) {
    int tid = threadIdx.x;
    int wave = tid >> 6, lane = tid & 63;
    int qid = lane >> 4, ql = lane & 15;
    float4 bb = *(const float4*)&b2[ql * 4];
    int n0 = blockIdx.x * 32;
    int nb = n0 + wave * 8;

    #pragma unroll 1
    for (int ip = 0; ip < 8; ip += 2) {
        int nA = nb + ip, nB = nA + 1;
        int cA = counts[nA], cB = counts[nB];
        int rsA = rowptr[nA], rsB = rowptr[nB];
        float dnA = dis[nA], dnB = dis[nB];
        int cmA = cA < 64 ? cA : 64, cmB = cB < 64 ? cB : 64;
        int2 pA = (lane < cmA) ? csr[rsA + lane] : make_int2(0, 0);
        int2 pB = (lane < cmB) ? csr[rsB + lane] : make_int2(0, 0);
        float a0 = 0.f, a1 = 0.f, a2 = 0.f, a3 = 0.f;
        float b0 = 0.f, b1v = 0.f, b2v = 0.f, b3 = 0.f;
        uint2 vSA, vSB;
        GATHER_PAIR(t2y, pA, pB, nA, nB, cmA, cmB,
                    a0, a1, a2, a3, b0, b1v, b2v, b3, vSA, vSB);
        if (cA > 64) {
            for (int jj = 64; jj < cA; ++jj) {
                int2 p = csr[rsA + jj];
                float f = __int_as_float(p.y);
                uint2 v = t2y[((unsigned)p.x << 4) | ql];
                if (qid == 0) {
                    a0 += f * blo(v.x); a1 += f * bhi(v.x);
                    a2 += f * blo(v.y); a3 += f * bhi(v.y);
                }
            }
        }
        if (cB > 64) {
            for (int jj = 64; jj < cB; ++jj) {
                int2 p = csr[rsB + jj];
                float f = __int_as_float(p.y);
                uint2 v = t2y[((unsigned)p.x << 4) | ql];
                if (qid == 0) {
                    b0 += f * blo(v.x); b1v += f * bhi(v.x);
                    b2v += f * blo(v.y); b3 += f * bhi(v.y);
                }
            }
        }
        if (qid == 0) {
            float oa0 = fmaxf(fmaf(dnA, a0 + blo(vSA.x), bb.x), 0.f);
            float oa1 = fmaxf(fmaf(dnA, a1 + bhi(vSA.x), bb.y), 0.f);
            float oa2 = fmaxf(fmaf(dnA, a2 + blo(vSA.y), bb.z), 0.f);
            float oa3 = fmaxf(fmaf(dnA, a3 + bhi(vSA.y), bb.w), 0.f);
            float ob0 = fmaxf(fmaf(dnB, b0 + blo(vSB.x), bb.x), 0.f);
            float ob1 = fmaxf(fmaf(dnB, b1v + bhi(vSB.x), bb.y), 0.f);
            float ob2 = fmaxf(fmaf(dnB, b2v + blo(vSB.y), bb.z), 0.f);
            float ob3 = fmaxf(fmaf(dnB, b3 + bhi(vSB.y), bb.w), 0.f);
            *(uint2*)&h2b[((unsigned)nA << 6) | (ql * 4)] =
                make_uint2(pack2(oa0, oa1), pack2(oa2, oa3));
            *(uint2*)&h2b[((unsigned)nB << 6) | (ql * 4)] =
                make_uint2(pack2(ob0, ob1), pack2(ob2, ob3));
        }
    }
}

// ---------------- FC + softmax (bf16 h2) ----------------
// r11: 4 graphs per 1024-thread block (quarter q = t>>8 owns graph 4b+q).
// The four quarters read the SAME 16KB Wfc slice per j-step -> L1-hot, so
// Wfc L2 traffic drops 4x (512MB -> 128MB across the launch).

__global__ __launch_bounds__(1024) void k_fc(
        const unsigned short* __restrict__ h2b, const float* __restrict__ Wfc,
        const float* __restrict__ bfc, float* __restrict__ out) {
    __shared__ float4 red[16];
    int b = blockIdx.x, t = threadIdx.x;
    int wave = t >> 6, lane = t & 63;
    int q = t >> 8, tt = t & 255;
    int g = b * 4 + q;
    const uint2* hrow = (const uint2*)(h2b + (size_t)g * (HID * NODESG));
    const float4* W4 = (const float4*)Wfc;
    float4 a = make_float4(0.f, 0.f, 0.f, 0.f);
    #pragma unroll
    for (int j = 0; j < 8; ++j) {
        int i = j * 256 + tt;                   // uint2 index: 4 channels
        uint2 hv = hrow[i];
        float h0 = blo(hv.x), h1 = bhi(hv.x), h2v = blo(hv.y), h3 = bhi(hv.y);
        float4 w0 = W4[i * 4 + 0];
        float4 w1 = W4[i * 4 + 1];
        float4 w2 = W4[i * 4 + 2];
        float4 w3 = W4[i * 4 + 3];
        a.x = fmaf(h0, w0.x, a.x); a.y = fmaf(h0, w0.y, a.y);
        a.z = fmaf(h0, w0.z, a.z); a.w = fmaf(h0, w0.w, a.w);
        a.x = fmaf(h1, w1.x, a.x); a.y = fmaf(h1, w1.y, a.y);
        a.z = fmaf(h1, w1.z, a.z); a.w = fmaf(h1, w1.w, a.w);
        a.x = fmaf(h2v, w2.x, a.x); a.y = fmaf(h2v, w2.y, a.y);
        a.z = fmaf(h2v, w2.z, a.z); a.w = fmaf(h2v, w2.w, a.w);
        a.x = fmaf(h3, w3.x, a.x); a.y = fmaf(h3, w3.y, a.y);
        a.z = fmaf(h3, w3.z, a.z); a.w = fmaf(h3, w3.w, a.w);
    }
    #pragma unroll
    for (int off = 1; off < 64; off <<= 1) {
        a.x += __shfl_xor(a.x, off);
        a.y += __shfl_xor(a.y, off);
        a.z += __shfl_xor(a.z, off);
        a.w += __shfl_xor(a.w, off);
    }
    if (lane == 0) red[wave] = a;
    __syncthreads();
    if (tt == 0) {                               // one thread per quarter
        int w0i = 4 * q;
        float l0 = red[w0i].x + red[w0i+1].x + red[w0i+2].x + red[w0i+3].x + bfc[0];
        float l1 = red[w0i].y + red[w0i+1].y + red[w0i+2].y + red[w0i+3].y + bfc[1];
        float l2 = red[w0i].z + red[w0i+1].z + red[w0i+2].z + red[w0i+3].z + bfc[2];
        float l3 = red[w0i].w + red[w0i+1].w + red[w0i+2].w + red[w0i+3].w + bfc[3];
        float mx = fmaxf(fmaxf(l0, l1), fmaxf(l2, l3));
        float e0 = expf(l0 - mx), e1 = expf(l1 - mx);
        float e2 = expf(l2 - mx), e3 = expf(l3 - mx);
        float inv = 1.f / (e0 + e1 + e2 + e3);
        float4 o = make_float4(e0 * inv, e1 * inv, e2 * inv, e3 * inv);
        *(float4*)&out[(size_t)g * 4] = o;
    }
}

// ---------------- launch ----------------
// r11 launch graph: 7 kernels; k_bucket and k_fc now 1024-thread blocks.

extern "C" void kernel_launch(void* const* d_in, const int* in_sizes, int n_in,
                              void* d_out, int out_size, void* d_ws, size_t ws_size,
                              hipStream_t stream) {
    const float* x   = (const float*)d_in[0];
    const int*   ei  = (const int*)  d_in[1];
    const float* ea  = (const float*)d_in[2];
    const float* W1  = (const float*)d_in[3];
    const float* b1  = (const float*)d_in[4];
    const float* W2  = (const float*)d_in[5];
    const float* b2  = (const float*)d_in[6];
    const float* Wfc = (const float*)d_in[7];
    const float* bfc = (const float*)d_in[8];
    float* out = (float*)d_out;
    const int* src = ei;
    const int* dst = ei + NE;

    char* ws = (char*)d_ws;
    size_t off = 0;
    int*   hist   = (int*)  (ws + off); off += (size_t)NBUCK * HBLK * 4;  // 1 MB
    int*   partial= (int*)  (ws + off); off += 4096;
    int*   counts = (int*)  (ws + off); off += (size_t)N_NODES * 4;
    int*   rowptr = (int*)  (ws + off); off += (size_t)N_NODES * 4;
    float* dis    = (float*)(ws + off); off += (size_t)N_NODES * 4;
    unsigned short* wf1 = (unsigned short*)(ws + off); off += 8192 * 2;   // 16 KB
    unsigned short* wf2 = (unsigned short*)(ws + off); off += 8192 * 2;   // 16 KB
    int2*  csr    = (int2*) (ws + off); off += (size_t)NE * 8;
    uint2* xb2    = (uint2*)(ws + off); off += (size_t)N_NODES * CIN * 2;
    unsigned short* t2u = (unsigned short*)(ws + off); off += (size_t)N_NODES * HID * 2;
    unsigned short* h2b = (unsigned short*)(ws + off); off += (size_t)N_NODES * HID * 2;
    unsigned long long* part = (unsigned long long*)t2u; // 16MB <= 16.7MB; dead before k_layer1

    k_hist   <<<HBLK + 8, 256, 0, stream>>>(dst, hist, W1, W2, wf1, wf2);
    k_scan1  <<<NBUCK * HBLK / 512, 256, 0, stream>>>(hist, hist, partial);
    k_scatter<<<HBLK, 256, 0, stream>>>(src, dst, ea, hist, partial, part);
    k_bucket <<<NBUCK, 1024, 0, stream>>>(part, hist, partial, csr, rowptr, counts,
                                          dis, x, xb2);
    k_layer1 <<<N_NODES / 32, 256, 0, stream>>>(xb2, csr, rowptr, counts, dis,
                                                wf1, wf2, b1, t2u);
    k_agg2   <<<N_NODES / 32, 256, 0, stream>>>((const uint2*)t2u, csr, rowptr,
                                                counts, dis, b2, h2b);
    k_fc     <<<NGRAPH / 4, 1024, 0, stream>>>(h2b, Wfc, bfc, out);
}